// Round 7
// baseline (1368.061 us; speedup 1.0000x reference)
//
#include <hip/hip_runtime.h>
#include <math.h>

typedef __attribute__((ext_vector_type(8))) short bf16x8;
typedef __attribute__((ext_vector_type(4))) float f32x4;

// ---------------- workspace layout ----------------
// ushort region (bf16 packed weights), offsets in ushorts:
#define UOFF_CAW 0L        // conv A  [l8][mp4][tap9][ic4][split2][mt2][lane64][e8] = 2359296 bf16
#define UOFF_GW  2359296L  // G A [l8][wv16][f3][ic4][split2][lane64][e8]           = 1572864 bf16
#define UOFF_W2F 3932160L  // pred2/cls2 A [blk2][mfr4][ic8][split2][lane64][e8]    =   65536 bf16
#define NB_TOT   3997696L  // total bf16 elems (= 1998848 floats)
// float region, offsets in floats:
#define OFF_W1G  1998848L  // [c256][o512] = 131072
#define REPACK_N 4128768L  // NB_TOT + 131072

// ---------------- helpers ----------------
__device__ inline ushort f2bf_rne(float x) {
  uint u = __float_as_uint(x);
  return (ushort)((u + 0x7FFFu + ((u >> 16) & 1u)) >> 16);
}
__device__ inline void split_bf(float x, ushort& h, ushort& l) {
  uint u = __float_as_uint(x);
  uint hb = (u + 0x7FFFu + ((u >> 16) & 1u)) & 0xFFFF0000u;
  h = (ushort)(hb >> 16);
  l = f2bf_rne(x - __uint_as_float(hb));
}
__device__ inline ushort bfsel(float w, int split) {
  uint u = __float_as_uint(w);
  uint hb = (u + 0x7FFFu + ((u >> 16) & 1u)) & 0xFFFF0000u;
  if (split == 0) return (ushort)(hb >> 16);
  float lo = w - __uint_as_float(hb);
  uint ul = __float_as_uint(lo);
  return (ushort)((ul + 0x7FFFu + ((ul >> 16) & 1u)) >> 16);
}
__device__ inline bf16x8 asb(uint4 a) {
  union { uint4 u; bf16x8 v; } x; x.u = a; return x.v;
}
__device__ inline f32x4 MFMA_(bf16x8 a, bf16x8 b, f32x4 c) {
  return __builtin_amdgcn_mfma_f32_16x16x32_bf16(a, b, c, 0, 0, 0);
}
// lgkm-only barrier: does NOT drain vmcnt (weight loads stay in flight).
__device__ inline void bar_lgkm() {
  asm volatile("s_waitcnt lgkmcnt(0)" ::: "memory");
  __builtin_amdgcn_s_barrier();
}

// Conv-image LDS layout (64 KB): per position p (128 rows of 512 B), 16 hi-granules (16 B) + 16 lo.
// Granule (ic,g) holds bf16 of ch ic*32 + {4g..4g+3, 16+4g..16+4g+3} at byte (ic*64+g*16) ^ ((p&7)<<4);
// lo-plane at +256 B.
__device__ inline void read_frag_pair(const char* xb, int pc, int g, int ic,
                                      bf16x8& bh, bf16x8& bl) {
  const int s0 = (pc & 7) << 4;
  const char* a = xb + pc * 512 + (((ic * 64 + (g << 4))) ^ s0);
  bh = asb(*(const uint4*)a);
  bl = asb(*(const uint4*)(a + 256));
}

// ---------------- repack ----------------
__global__ void k_repack(const float* __restrict__ head_w, const float* __restrict__ res_w,
                         const float* __restrict__ fusion_w,
                         const float* __restrict__ pred1_w, const float* __restrict__ cls1_w,
                         const float* __restrict__ pred2_w, const float* __restrict__ cls2_w,
                         float* __restrict__ ws) {
  const long j = (long)blockIdx.x * 256 + threadIdx.x;
  if (j >= REPACK_N) return;
  if (j < NB_TOT) {
    ushort* wsu = (ushort*)ws;
    float w;
    if (j < UOFF_GW) {                        // CAW
      int e = (int)(j & 7); long q = j >> 3;
      int lane = (int)(q & 63); q >>= 6;
      int mt = (int)(q & 1); q >>= 1;
      int split = (int)(q & 1); q >>= 1;
      int ic = (int)(q & 3); q >>= 2;
      int tap = (int)(q % 9); q /= 9;
      int mp = (int)(q & 3); int l = (int)(q >> 2);
      int gg = lane >> 4;
      int kl = (e < 4) ? (4 * gg + e) : (16 + 4 * gg + e - 4);
      int m = mp * 32 + mt * 16 + (lane & 15);
      int i = ic * 32 + kl;
      if (l == 0) w = (i < 67) ? head_w[((long)m * 67 + i) * 9 + tap] : 0.f;
      else        w = res_w[(((long)(l - 1) * 128 + m) * 128 + i) * 9 + tap];
      wsu[j] = bfsel(w, split);
    } else if (j < UOFF_W2F) {                // GW = [fusion_w; pred1|cls1 state part]
      long jj = j - UOFF_GW;
      int e = (int)(jj & 7); long q = jj >> 3;
      int lane = (int)(q & 63); q >>= 6;
      int split = (int)(q & 1); q >>= 1;
      int ic = (int)(q & 3); q >>= 2;
      int f = (int)(q % 3); q /= 3;
      int wv = (int)(q & 15); int l = (int)(q >> 4);
      int gg = lane >> 4;
      int kl = (e < 4) ? (4 * gg + e) : (16 + 4 * gg + e - 4);
      int grow = wv * 48 + f * 16 + (lane & 15);
      int k = ic * 32 + kl;
      if (grow < 256)      w = fusion_w[(long)grow * 1024 + l * 128 + k];
      else if (grow < 512) w = pred1_w[(long)(grow - 256) * 1280 + 256 + l * 128 + k];
      else                 w = cls1_w[(long)(grow - 512) * 1280 + 256 + l * 128 + k];
      wsu[j] = bfsel(w, split);
    } else {                                  // W2F (pred2/cls2 A-fragments)
      long jj = j - UOFF_W2F;
      int e = (int)(jj & 7); long q = jj >> 3;
      int lane = (int)(q & 63); q >>= 6;
      int split = (int)(q & 1); q >>= 1;
      int ic = (int)(q & 7); q >>= 3;
      int mfr = (int)(q & 3); int blk = (int)(q >> 2);
      int gg = lane >> 4;
      int kl = (e < 4) ? (4 * gg + e) : (16 + 4 * gg + e - 4);
      int m = mfr * 16 + (lane & 15);
      int k = ic * 32 + kl;
      w = blk ? cls2_w[(long)m * 256 + k] : pred2_w[(long)m * 256 + k];
      wsu[j] = bfsel(w, split);
    }
  } else {                                    // W1G (fp32)
    long q = j - NB_TOT; int o = (int)(q & 511); int c = (int)(q >> 9);
    ws[OFF_W1G + q] = (o < 256) ? pred1_w[(long)o * 1280 + c] : cls1_w[(long)(o - 256) * 1280 + c];
  }
}

// ================ fully fused: gather + conv chain + incremental G(fusion+h1) + heads + NMS ================
__global__ __launch_bounds__(1024) __attribute__((amdgpu_waves_per_eu(4)))
void k_fused(const float* __restrict__ cnn, const float* __restrict__ i_it,
             const float* __restrict__ c_it, const float* __restrict__ cls_in,
             const int* __restrict__ ind,
             const ushort* __restrict__ CAW, const ushort* __restrict__ GW,
             const ushort* __restrict__ W2F,
             const float* __restrict__ head_b, const float* __restrict__ res_b,
             const float* __restrict__ fus_b, const float* __restrict__ W1G,
             const float* __restrict__ p1b, const float* __restrict__ c1b,
             const float* __restrict__ p2b, const float* __restrict__ c2b,
             const float* __restrict__ p3w, const float* __restrict__ p3b,
             const float* __restrict__ c3w, const float* __restrict__ c3b,
             float* __restrict__ out) {
  __shared__ uint4 xt4[4096];   // 64 KB granule image (x-tile, then h1-quarter image, then h2)
  __shared__ float scr[256];
  __shared__ float sg[256];
  __shared__ float hg_s[512];
  char* xb = (char*)xt4;
  const int n = blockIdx.x, t = threadIdx.x;
  const int lane = t & 63, li = lane & 15, g = lane >> 4;
  const int wv = __builtin_amdgcn_readfirstlane(t >> 6);
  const int mp = wv & 3, np = wv >> 2;     // conv: M=32 ch x N=32 pos per wave
  const int mw = wv & 7, qw = wv >> 3;     // phase C read tiling

  // ---- bilinear gather -> LDS fragment granules ----
  {
    const int p = t & 127, qg = t >> 7;
    const long nb = (long)n * 128 + p;
    const int sw = p & 7;
    if (qg < 4) {
      const float gx = i_it[nb * 2 + 0] - 0.5f;
      const float gy = i_it[nb * 2 + 1] - 0.5f;
      const float fx = floorf(gx), fy = floorf(gy);
      const float wx = gx - fx, wy = gy - fy;
      const int x0 = (int)fx, y0 = (int)fy, x1 = x0 + 1, y1 = y0 + 1;
      const bool vx0 = (x0 >= 0) & (x0 < 128), vx1 = (x1 >= 0) & (x1 < 128);
      const bool vy0 = (y0 >= 0) & (y0 < 128), vy1 = (y1 >= 0) & (y1 < 128);
      const int x0c = min(max(x0, 0), 127), x1c = min(max(x1, 0), 127);
      const int y0c = min(max(y0, 0), 127), y1c = min(max(y1, 0), 127);
      const float w00 = (vx0 && vy0) ? (1.f - wx) * (1.f - wy) : 0.f;
      const float w01 = (vx1 && vy0) ? wx * (1.f - wy) : 0.f;
      const float w10 = (vx0 && vy1) ? (1.f - wx) * wy : 0.f;
      const float w11 = (vx1 && vy1) ? wx * wy : 0.f;
      const long base = (long)ind[n] * (64L * 16384);
      const int a00 = y0c * 128 + x0c, a01 = y0c * 128 + x1c;
      const int a10 = y1c * 128 + x0c, a11 = y1c * 128 + x1c;
#pragma unroll
      for (int qq = 0; qq < 4; qq++) {
        ushort hh[4], ll[4];
#pragma unroll
        for (int cc = 0; cc < 4; cc++) {
          const int c = qg * 16 + qq * 4 + cc;
          const float* f = cnn + base + (long)c * 16384;
          float x = f[a00] * w00 + f[a01] * w01 + f[a10] * w10 + f[a11] * w11;
          split_bf(x, hh[cc], ll[cc]);
        }
        const int G = ((qg >> 1) * 4 + qq) ^ sw;
        char* a = xb + p * 512 + G * 16 + (qg & 1) * 8;
        *(uint2*)a = make_uint2((uint)hh[0] | ((uint)hh[1] << 16), (uint)hh[2] | ((uint)hh[3] << 16));
        *(uint2*)(a + 256) = make_uint2((uint)ll[0] | ((uint)ll[1] << 16), (uint)ll[2] | ((uint)ll[3] << 16));
      }
    } else {
#pragma unroll
      for (int qq = 0; qq < 4; qq++) {
        ushort hh[4], ll[4];
        if (qg == 4 && qq == 0) {
          float v0 = c_it[nb * 2 + 0] * 4.f, v1 = c_it[nb * 2 + 1] * 4.f, v2 = cls_in[nb];
          split_bf(v0, hh[0], ll[0]); split_bf(v1, hh[1], ll[1]); split_bf(v2, hh[2], ll[2]);
          hh[3] = 0; ll[3] = 0;
        } else {
          hh[0] = hh[1] = hh[2] = hh[3] = 0; ll[0] = ll[1] = ll[2] = ll[3] = 0;
        }
        const int G = ((qg >> 1) * 4 + qq) ^ sw;
        char* a = xb + p * 512 + G * 16 + (qg & 1) * 8;
        *(uint2*)a = make_uint2((uint)hh[0] | ((uint)hh[1] << 16), (uint)hh[2] | ((uint)hh[3] << 16));
        *(uint2*)(a + 256) = make_uint2((uint)ll[0] | ((uint)ll[1] << 16), (uint)ll[2] | ((uint)ll[3] << 16));
      }
    }
  }
  __syncthreads();

  const f32x4 fz = {0.f, 0.f, 0.f, 0.f};
  // G accumulator: rows wv*48 + f*16 + g*4 + e (0..767: <256 fusion, >=256 h1), pos nt*16+li
  f32x4 acc[3][8];
#pragma unroll
  for (int f = 0; f < 3; f++)
#pragma unroll
    for (int c = 0; c < 8; c++) acc[f][c] = fz;

  const uint4* caw = (const uint4*)CAW;
  const uint4* gaw = (const uint4*)GW;

  for (int l = 0; l < 8; l++) {
    const int dil = (l >= 6) ? 4 : ((l >= 4) ? 2 : 1);
    const int nic = (l == 0) ? 3 : 4;
    // ======== READ REGION: G-update(l-1) + conv(l), both read xt = x_{l-1} ========
    if (l > 0) {
      const uint4* gwl = gaw + ((long)((l - 1) * 16 + wv)) * 1536 + lane;
#pragma unroll
      for (int ic = 0; ic < 4; ic++) {
        const uint4* w0 = gwl + (0 * 4 + ic) * 128;
        const uint4* w1 = gwl + (1 * 4 + ic) * 128;
        const uint4* w2p = gwl + (2 * 4 + ic) * 128;
        const bf16x8 Ah0 = asb(w0[0]), Al0 = asb(w0[64]);
        const bf16x8 Ah1 = asb(w1[0]), Al1 = asb(w1[64]);
        const bf16x8 Ah2 = asb(w2p[0]), Al2 = asb(w2p[64]);
#pragma unroll
        for (int nt = 0; nt < 8; nt++) {
          const int pc = nt * 16 + li;
          bf16x8 bh, bl;
          read_frag_pair(xb, pc, g, ic, bh, bl);
          acc[0][nt] = MFMA_(Ah0, bh, acc[0][nt]);
          acc[1][nt] = MFMA_(Ah1, bh, acc[1][nt]);
          acc[2][nt] = MFMA_(Ah2, bh, acc[2][nt]);
          acc[0][nt] = MFMA_(Ah0, bl, acc[0][nt]);
          acc[1][nt] = MFMA_(Ah1, bl, acc[1][nt]);
          acc[2][nt] = MFMA_(Ah2, bl, acc[2][nt]);
          acc[0][nt] = MFMA_(Al0, bh, acc[0][nt]);
          acc[1][nt] = MFMA_(Al1, bh, acc[1][nt]);
          acc[2][nt] = MFMA_(Al2, bh, acc[2][nt]);
        }
      }
    }
    // conv(l)
    f32x4 cacc[2][2];
    cacc[0][0] = fz; cacc[0][1] = fz; cacc[1][0] = fz; cacc[1][1] = fz;
    const uint4* cawl = caw + ((long)(l * 4 + mp)) * 9216;
    for (int tap = 0; tap < 9; tap++) {
      const int shift = (tap - 4) * dil;
      const int pc0 = (np * 32 + li + shift + 128) & 127;
      const int pc1 = (np * 32 + 16 + li + shift + 128) & 127;
      const uint4* cawt = cawl + tap * 1024 + lane;
      for (int ic = 0; ic < nic; ic++) {
        const uint4* w0 = cawt + ic * 256;
        const bf16x8 Ah0 = asb(w0[0]),   Ah1 = asb(w0[64]);
        const bf16x8 Al0 = asb(w0[128]), Al1 = asb(w0[192]);
        bf16x8 bh, bl;
        read_frag_pair(xb, pc0, g, ic, bh, bl);
        cacc[0][0] = MFMA_(Ah0, bh, cacc[0][0]);
        cacc[1][0] = MFMA_(Ah1, bh, cacc[1][0]);
        cacc[0][0] = MFMA_(Ah0, bl, cacc[0][0]);
        cacc[1][0] = MFMA_(Ah1, bl, cacc[1][0]);
        cacc[0][0] = MFMA_(Al0, bh, cacc[0][0]);
        cacc[1][0] = MFMA_(Al1, bh, cacc[1][0]);
        read_frag_pair(xb, pc1, g, ic, bh, bl);
        cacc[0][1] = MFMA_(Ah0, bh, cacc[0][1]);
        cacc[1][1] = MFMA_(Ah1, bh, cacc[1][1]);
        cacc[0][1] = MFMA_(Ah0, bl, cacc[0][1]);
        cacc[1][1] = MFMA_(Ah1, bl, cacc[1][1]);
        cacc[0][1] = MFMA_(Al0, bh, cacc[0][1]);
        cacc[1][1] = MFMA_(Al1, bh, cacc[1][1]);
      }
    }
    bar_lgkm();
    // ======== EPILOGUE: bias + relu + residual -> xt granules ========
    {
      const float* bsrc = (l == 0) ? head_b : (res_b + (l - 1) * 128);
      const float4 b0 = *(const float4*)&bsrc[mp * 32 + g * 4];
      const float4 b1 = *(const float4*)&bsrc[mp * 32 + 16 + g * 4];
#pragma unroll
      for (int nt = 0; nt < 2; nt++) {
        const int p = np * 32 + nt * 16 + li;
        const int X = (mp * 64 + g * 16) ^ ((p & 7) << 4);
        char* a = xb + p * 512 + X;
        float v[8];
        v[0] = fmaxf(cacc[0][nt][0] + b0.x, 0.f);
        v[1] = fmaxf(cacc[0][nt][1] + b0.y, 0.f);
        v[2] = fmaxf(cacc[0][nt][2] + b0.z, 0.f);
        v[3] = fmaxf(cacc[0][nt][3] + b0.w, 0.f);
        v[4] = fmaxf(cacc[1][nt][0] + b1.x, 0.f);
        v[5] = fmaxf(cacc[1][nt][1] + b1.y, 0.f);
        v[6] = fmaxf(cacc[1][nt][2] + b1.z, 0.f);
        v[7] = fmaxf(cacc[1][nt][3] + b1.w, 0.f);
        if (l > 0) {
          const uint4 oh = *(const uint4*)a;
          const uint4 ol = *(const uint4*)(a + 256);
          const uint hw[4] = {oh.x, oh.y, oh.z, oh.w};
          const uint lw[4] = {ol.x, ol.y, ol.z, ol.w};
#pragma unroll
          for (int k = 0; k < 8; k++) {
            const uint hh = (k & 1) ? (hw[k >> 1] & 0xFFFF0000u) : ((hw[k >> 1] & 0xFFFFu) << 16);
            const uint ll = (k & 1) ? (lw[k >> 1] & 0xFFFF0000u) : ((lw[k >> 1] & 0xFFFFu) << 16);
            v[k] += __uint_as_float(hh) + __uint_as_float(ll);
          }
        }
        ushort hh[8], ll[8];
#pragma unroll
        for (int k = 0; k < 8; k++) split_bf(v[k], hh[k], ll[k]);
        *(uint4*)a = make_uint4((uint)hh[0] | ((uint)hh[1] << 16), (uint)hh[2] | ((uint)hh[3] << 16),
                                (uint)hh[4] | ((uint)hh[5] << 16), (uint)hh[6] | ((uint)hh[7] << 16));
        *(uint4*)(a + 256) = make_uint4((uint)ll[0] | ((uint)ll[1] << 16), (uint)ll[2] | ((uint)ll[3] << 16),
                                        (uint)ll[4] | ((uint)ll[5] << 16), (uint)ll[6] | ((uint)ll[7] << 16));
      }
    }
    __syncthreads();
  }

  // ======== tail G-update on x_7 (still in xt) ========
  {
    const uint4* gwl = gaw + ((long)(7 * 16 + wv)) * 1536 + lane;
#pragma unroll
    for (int ic = 0; ic < 4; ic++) {
      const uint4* w0 = gwl + (0 * 4 + ic) * 128;
      const uint4* w1 = gwl + (1 * 4 + ic) * 128;
      const uint4* w2p = gwl + (2 * 4 + ic) * 128;
      const bf16x8 Ah0 = asb(w0[0]), Al0 = asb(w0[64]);
      const bf16x8 Ah1 = asb(w1[0]), Al1 = asb(w1[64]);
      const bf16x8 Ah2 = asb(w2p[0]), Al2 = asb(w2p[64]);
#pragma unroll
      for (int nt = 0; nt < 8; nt++) {
        const int pc = nt * 16 + li;
        bf16x8 bh, bl;
        read_frag_pair(xb, pc, g, ic, bh, bl);
        acc[0][nt] = MFMA_(Ah0, bh, acc[0][nt]);
        acc[1][nt] = MFMA_(Ah1, bh, acc[1][nt]);
        acc[2][nt] = MFMA_(Ah2, bh, acc[2][nt]);
        acc[0][nt] = MFMA_(Ah0, bl, acc[0][nt]);
        acc[1][nt] = MFMA_(Ah1, bl, acc[1][nt]);
        acc[2][nt] = MFMA_(Ah2, bl, acc[2][nt]);
        acc[0][nt] = MFMA_(Al0, bh, acc[0][nt]);
        acc[1][nt] = MFMA_(Al1, bh, acc[1][nt]);
        acc[2][nt] = MFMA_(Al2, bh, acc[2][nt]);
      }
    }
  }

  // ---- fusion rows (<256): max over all 128 positions -> scr ----
#pragma unroll
  for (int f = 0; f < 3; f++) {
    const int base = wv * 48 + f * 16;
    if (base < 256) {
#pragma unroll
      for (int e = 0; e < 4; e++) {
        float m = acc[f][0][e];
#pragma unroll
        for (int nt = 1; nt < 8; nt++) m = fmaxf(m, acc[f][nt][e]);
#pragma unroll
        for (int s = 1; s < 16; s <<= 1) m = fmaxf(m, __shfl_xor(m, s, 64));
        if (li == 0) scr[base + g * 4 + e] = m;
      }
    }
  }
  bar_lgkm();
  if (t < 256) sg[t] = scr[t] + fus_b[t];
  bar_lgkm();

  // ---- hg[512] = bias + W1G^T (sg) ----
  if (t < 512) {
    float s = (t < 256) ? p1b[t] : c1b[t - 256];
    const float* w = W1G + t;
#pragma unroll 8
    for (int c = 0; c < 256; c++) s = fmaf(w[(long)c * 512], sg[c], s);
    hg_s[t] = s;
  }
  bar_lgkm();

  // ---- h1 rows (>=256): bias + relu in regs ----
#pragma unroll
  for (int f = 0; f < 3; f++) {
    const int base = wv * 48 + f * 16;
    if (base >= 256) {
      const float4 hq = *(const float4*)&hg_s[base - 256 + g * 4];
#pragma unroll
      for (int nt = 0; nt < 8; nt++) {
        acc[f][nt][0] = fmaxf(acc[f][nt][0] + hq.x, 0.f);
        acc[f][nt][1] = fmaxf(acc[f][nt][1] + hq.y, 0.f);
        acc[f][nt][2] = fmaxf(acc[f][nt][2] + hq.z, 0.f);
        acc[f][nt][3] = fmaxf(acc[f][nt][3] + hq.w, 0.f);
      }
    }
  }

  // ---- phase C: h2 = relu(W2 @ h1 + b2), 4 pos-quarters via K=512 granule image in xt ----
  // quarter image: pos pl (32 rows of 2 KB): hi granule at pl*2048 + ((kc*64+gp*16)^((pl&7)<<4)) + half*8, lo +1024
  const uint4* w2 = (const uint4*)W2F;
  f32x4 a2q[4];
  for (int q = 0; q < 4; q++) {
    a2q[q] = fz;
    // stage h1 cells for nt in {2q, 2q+1}
#pragma unroll
    for (int f = 0; f < 3; f++) {
      const int base = wv * 48 + f * 16;
      if (base >= 256) {
        const int r1b = base - 256 + g * 4;      // 4-aligned k-index of elems e=0..3
        const int kc = r1b >> 5;
        const int kic = r1b & 31;
        const int gp = (kic & 15) >> 2;
        const int half = kic >> 4;
#pragma unroll
        for (int ntl = 0; ntl < 2; ntl++) {
          const int nt = 2 * q + ntl;
          const int pl = ntl * 16 + li;
          char* a = xb + pl * 2048 + ((kc * 64 + gp * 16) ^ ((pl & 7) << 4)) + half * 8;
          ushort hh[4], ll[4];
          split_bf(acc[f][nt][0], hh[0], ll[0]);
          split_bf(acc[f][nt][1], hh[1], ll[1]);
          split_bf(acc[f][nt][2], hh[2], ll[2]);
          split_bf(acc[f][nt][3], hh[3], ll[3]);
          *(uint2*)a = make_uint2((uint)hh[0] | ((uint)hh[1] << 16), (uint)hh[2] | ((uint)hh[3] << 16));
          *(uint2*)(a + 1024) = make_uint2((uint)ll[0] | ((uint)ll[1] << 16), (uint)ll[2] | ((uint)ll[3] << 16));
        }
      }
    }
    bar_lgkm();
    // read: out-row frag mw (0..3 pred2, 4..7 cls2); pos pl = qw*16 + li
    {
      const int blkc = mw >> 2;
      const int pl = qw * 16 + li;
#pragma unroll
      for (int ic8 = 0; ic8 < 8; ic8++) {
        const int kc = blkc * 8 + ic8;
        const uint4* wb = w2 + (((long)(blkc * 4 + (mw & 3)) * 8 + ic8) * 2) * 64 + lane;
        const bf16x8 Ah = asb(wb[0]), Al = asb(wb[64]);
        const char* ba = xb + pl * 2048 + ((kc * 64 + g * 16) ^ ((pl & 7) << 4));
        const bf16x8 bh = asb(*(const uint4*)ba);
        const bf16x8 bl = asb(*(const uint4*)(ba + 1024));
        a2q[q] = MFMA_(Ah, bh, a2q[q]);
        a2q[q] = MFMA_(Ah, bl, a2q[q]);
        a2q[q] = MFMA_(Al, bh, a2q[q]);
      }
    }
    bar_lgkm();   // reads done before next quarter's writers overwrite
  }

  // ---- h2 -> LDS floats (overwrite xt) ----
  {
    float* h2L = (float*)xb;
#pragma unroll
    for (int q = 0; q < 4; q++) {
#pragma unroll
      for (int e = 0; e < 4; e++) {
        const int row = mw * 16 + g * 4 + e;
        const float bb = (mw < 4) ? p2b[row] : c2b[row - 64];
        h2L[row * 128 + q * 32 + qw * 16 + li] = fmaxf(a2q[q][e] + bb, 0.f);
      }
    }
  }
  bar_lgkm();

  // ---- tail: pred3/cls3 + outputs + NMS ----
  {
    const float* h2L = (const float*)xb;
    float sig = 0.f;
    const int pp = t & 127;
    if (t < 128) {
      float o0v = p3b[0], o1v = p3b[1], cv = c3b[0];
      for (int j = 0; j < 64; j++) {
        const float hp = h2L[j * 128 + pp];
        const float hc = h2L[(64 + j) * 128 + pp];
        o0v = fmaf(p3w[j], hp, o0v);
        o1v = fmaf(p3w[64 + j], hp, o1v);
        cv = fmaf(c3w[j], hc, cv);
      }
      const long ip = ((long)n * 128 + pp) * 2;
      out[ip + 0] = i_it[ip + 0] * 4.f + o0v;
      out[ip + 1] = i_it[ip + 1] * 4.f + o1v;
      out[131072 + (long)n * 128 + pp] = cv;
      sig = 1.f / (1.f + expf(-cv));
      scr[pp] = sig;
    }
    bar_lgkm();
    if (t < 128) {
      float m = scr[pp];
#pragma unroll
      for (int s = 1; s <= 2; s++) {
        m = fmaxf(m, scr[(pp + s) & 127]);
        m = fmaxf(m, scr[(pp + 128 - s) & 127]);
      }
      out[196608 + (long)n * 128 + pp] = (sig >= m) ? sig : 0.f;
    }
  }
}

extern "C" void kernel_launch(void* const* d_in, const int* in_sizes, int n_in,
                              void* d_out, int out_size, void* d_ws, size_t ws_size,
                              hipStream_t stream) {
  const float* cnn      = (const float*)d_in[0];
  const float* i_it     = (const float*)d_in[1];
  const float* c_it     = (const float*)d_in[2];
  const float* it_cls   = (const float*)d_in[3];
  const int*   ind      = (const int*)d_in[4];
  const float* head_w   = (const float*)d_in[5];
  const float* head_b   = (const float*)d_in[6];
  const float* res_w    = (const float*)d_in[7];
  const float* res_b    = (const float*)d_in[8];
  const float* fusion_w = (const float*)d_in[9];
  const float* fusion_b = (const float*)d_in[10];
  const float* pred1_w  = (const float*)d_in[11];
  const float* pred1_b  = (const float*)d_in[12];
  const float* pred2_w  = (const float*)d_in[13];
  const float* pred2_b  = (const float*)d_in[14];
  const float* pred3_w  = (const float*)d_in[15];
  const float* pred3_b  = (const float*)d_in[16];
  const float* cls1_w   = (const float*)d_in[17];
  const float* cls1_b   = (const float*)d_in[18];
  const float* cls2_w   = (const float*)d_in[19];
  const float* cls2_b   = (const float*)d_in[20];
  const float* cls3_w   = (const float*)d_in[21];
  const float* cls3_b   = (const float*)d_in[22];
  float* ws = (float*)d_ws;
  float* out = (float*)d_out;
  const ushort* wsu = (const ushort*)d_ws;

  k_repack<<<(int)((REPACK_N + 255) / 256), 256, 0, stream>>>(
      head_w, res_w, fusion_w, pred1_w, cls1_w, pred2_w, cls2_w, ws);

  k_fused<<<512, 1024, 0, stream>>>(cnn, i_it, c_it, it_cls, ind,
                                    wsu + UOFF_CAW, wsu + UOFF_GW, wsu + UOFF_W2F,
                                    head_b, res_b, fusion_b, ws + OFF_W1G,
                                    pred1_b, cls1_b, pred2_b, cls2_b,
                                    pred3_w, pred3_b, cls3_w, cls3_b, out);
}

// Round 8
// 1329.606 us; speedup vs baseline: 1.0289x; 1.0289x over previous
//
#include <hip/hip_runtime.h>
#include <math.h>

typedef __attribute__((ext_vector_type(8))) short bf16x8;
typedef __attribute__((ext_vector_type(4))) float f32x4;

// ---------------- workspace layout ----------------
// ushort region (bf16 packed weights), offsets in ushorts:
#define UOFF_CAW 0L        // conv A  [l8][mp4][tap9][ic4][split2][mt2][lane64][e8] = 2359296 bf16
#define UOFF_GW  2359296L  // G A [l8][wv16][f3][ic4][split2][lane64][e8]           = 1572864 bf16
#define UOFF_W2F 3932160L  // pred2/cls2 A [blk2][mfr4][ic8][split2][lane64][e8]    =   65536 bf16
#define NB_TOT   3997696L  // total bf16 elems (= 1998848 floats)
// float region, offsets in floats:
#define OFF_W1G  1998848L  // [c256][o512] = 131072
#define REPACK_N 4128768L  // NB_TOT + 131072

// ---------------- helpers ----------------
__device__ inline ushort f2bf_rne(float x) {
  uint u = __float_as_uint(x);
  return (ushort)((u + 0x7FFFu + ((u >> 16) & 1u)) >> 16);
}
__device__ inline void split_bf(float x, ushort& h, ushort& l) {
  uint u = __float_as_uint(x);
  uint hb = (u + 0x7FFFu + ((u >> 16) & 1u)) & 0xFFFF0000u;
  h = (ushort)(hb >> 16);
  l = f2bf_rne(x - __uint_as_float(hb));
}
__device__ inline ushort bfsel(float w, int split) {
  uint u = __float_as_uint(w);
  uint hb = (u + 0x7FFFu + ((u >> 16) & 1u)) & 0xFFFF0000u;
  if (split == 0) return (ushort)(hb >> 16);
  float lo = w - __uint_as_float(hb);
  uint ul = __float_as_uint(lo);
  return (ushort)((ul + 0x7FFFu + ((ul >> 16) & 1u)) >> 16);
}
__device__ inline bf16x8 asb(uint4 a) {
  union { uint4 u; bf16x8 v; } x; x.u = a; return x.v;
}
__device__ inline f32x4 MFMA_(bf16x8 a, bf16x8 b, f32x4 c) {
  return __builtin_amdgcn_mfma_f32_16x16x32_bf16(a, b, c, 0, 0, 0);
}
// lgkm-only barrier: does NOT drain vmcnt (weight loads stay in flight).
__device__ inline void bar_lgkm() {
  asm volatile("s_waitcnt lgkmcnt(0)" ::: "memory");
  __builtin_amdgcn_s_barrier();
}

// Conv-image LDS layout (64 KB): per position p (128 rows of 512 B), 16 hi-granules (16 B) + 16 lo.
// Granule (ic,g) holds bf16 of ch ic*32 + {4g..4g+3, 16+4g..16+4g+3} at byte (ic*64+g*16) ^ ((p&7)<<4);
// lo-plane at +256 B.
__device__ inline void read_frag_pair(const char* xb, int pc, int g, int ic,
                                      bf16x8& bh, bf16x8& bl) {
  const int s0 = (pc & 7) << 4;
  const char* a = xb + pc * 512 + (((ic * 64 + (g << 4))) ^ s0);
  bh = asb(*(const uint4*)a);
  bl = asb(*(const uint4*)(a + 256));
}

// ---------------- repack (unchanged from R7) ----------------
__global__ void k_repack(const float* __restrict__ head_w, const float* __restrict__ res_w,
                         const float* __restrict__ fusion_w,
                         const float* __restrict__ pred1_w, const float* __restrict__ cls1_w,
                         const float* __restrict__ pred2_w, const float* __restrict__ cls2_w,
                         float* __restrict__ ws) {
  const long j = (long)blockIdx.x * 256 + threadIdx.x;
  if (j >= REPACK_N) return;
  if (j < NB_TOT) {
    ushort* wsu = (ushort*)ws;
    float w;
    if (j < UOFF_GW) {                        // CAW
      int e = (int)(j & 7); long q = j >> 3;
      int lane = (int)(q & 63); q >>= 6;
      int mt = (int)(q & 1); q >>= 1;
      int split = (int)(q & 1); q >>= 1;
      int ic = (int)(q & 3); q >>= 2;
      int tap = (int)(q % 9); q /= 9;
      int mp = (int)(q & 3); int l = (int)(q >> 2);
      int gg = lane >> 4;
      int kl = (e < 4) ? (4 * gg + e) : (16 + 4 * gg + e - 4);
      int m = mp * 32 + mt * 16 + (lane & 15);
      int i = ic * 32 + kl;
      if (l == 0) w = (i < 67) ? head_w[((long)m * 67 + i) * 9 + tap] : 0.f;
      else        w = res_w[(((long)(l - 1) * 128 + m) * 128 + i) * 9 + tap];
      wsu[j] = bfsel(w, split);
    } else if (j < UOFF_W2F) {                // GW = [fusion_w; pred1|cls1 state part]
      long jj = j - UOFF_GW;
      int e = (int)(jj & 7); long q = jj >> 3;
      int lane = (int)(q & 63); q >>= 6;
      int split = (int)(q & 1); q >>= 1;
      int ic = (int)(q & 3); q >>= 2;
      int f = (int)(q % 3); q /= 3;
      int wv = (int)(q & 15); int l = (int)(q >> 4);
      int gg = lane >> 4;
      int kl = (e < 4) ? (4 * gg + e) : (16 + 4 * gg + e - 4);
      int grow = wv * 48 + f * 16 + (lane & 15);
      int k = ic * 32 + kl;
      if (grow < 256)      w = fusion_w[(long)grow * 1024 + l * 128 + k];
      else if (grow < 512) w = pred1_w[(long)(grow - 256) * 1280 + 256 + l * 128 + k];
      else                 w = cls1_w[(long)(grow - 512) * 1280 + 256 + l * 128 + k];
      wsu[j] = bfsel(w, split);
    } else {                                  // W2F (pred2/cls2 A-fragments)
      long jj = j - UOFF_W2F;
      int e = (int)(jj & 7); long q = jj >> 3;
      int lane = (int)(q & 63); q >>= 6;
      int split = (int)(q & 1); q >>= 1;
      int ic = (int)(q & 7); q >>= 3;
      int mfr = (int)(q & 3); int blk = (int)(q >> 2);
      int gg = lane >> 4;
      int kl = (e < 4) ? (4 * gg + e) : (16 + 4 * gg + e - 4);
      int m = mfr * 16 + (lane & 15);
      int k = ic * 32 + kl;
      w = blk ? cls2_w[(long)m * 256 + k] : pred2_w[(long)m * 256 + k];
      wsu[j] = bfsel(w, split);
    }
  } else {                                    // W1G (fp32)
    long q = j - NB_TOT; int o = (int)(q & 511); int c = (int)(q >> 9);
    ws[OFF_W1G + q] = (o < 256) ? pred1_w[(long)o * 1280 + c] : cls1_w[(long)(o - 256) * 1280 + c];
  }
}

// ================ fully fused: gather + conv chain + incremental G(fusion+h1) + heads + NMS ================
// waves_per_eu(4,4): exactly 4 waves/SIMD -> compiler may use the full 128-VGPR budget (acc stays in regs).
__global__ __launch_bounds__(1024) __attribute__((amdgpu_waves_per_eu(4, 4)))
void k_fused(const float* __restrict__ cnn, const float* __restrict__ i_it,
             const float* __restrict__ c_it, const float* __restrict__ cls_in,
             const int* __restrict__ ind,
             const ushort* __restrict__ CAW, const ushort* __restrict__ GW,
             const ushort* __restrict__ W2F,
             const float* __restrict__ head_b, const float* __restrict__ res_b,
             const float* __restrict__ fus_b, const float* __restrict__ W1G,
             const float* __restrict__ p1b, const float* __restrict__ c1b,
             const float* __restrict__ p2b, const float* __restrict__ c2b,
             const float* __restrict__ p3w, const float* __restrict__ p3b,
             const float* __restrict__ c3w, const float* __restrict__ c3b,
             float* __restrict__ out) {
  __shared__ uint4 xt4[4096];   // 64 KB granule image (x-tile, then h1-quarter image, then h2)
  __shared__ float scr[256];
  __shared__ float sg[256];
  __shared__ float hg_s[512];
  char* xb = (char*)xt4;
  const int n = blockIdx.x, t = threadIdx.x;
  const int lane = t & 63, li = lane & 15, g = lane >> 4;
  const int wv = __builtin_amdgcn_readfirstlane(t >> 6);
  const int mp = wv & 3, np = wv >> 2;     // conv: M=32 ch x N=32 pos per wave
  const int mw = wv & 7, qw = wv >> 3;     // phase C read tiling

  // ---- bilinear gather -> LDS fragment granules ----
  {
    const int p = t & 127, qg = t >> 7;
    const long nb = (long)n * 128 + p;
    const int sw = p & 7;
    if (qg < 4) {
      const float gx = i_it[nb * 2 + 0] - 0.5f;
      const float gy = i_it[nb * 2 + 1] - 0.5f;
      const float fx = floorf(gx), fy = floorf(gy);
      const float wx = gx - fx, wy = gy - fy;
      const int x0 = (int)fx, y0 = (int)fy, x1 = x0 + 1, y1 = y0 + 1;
      const bool vx0 = (x0 >= 0) & (x0 < 128), vx1 = (x1 >= 0) & (x1 < 128);
      const bool vy0 = (y0 >= 0) & (y0 < 128), vy1 = (y1 >= 0) & (y1 < 128);
      const int x0c = min(max(x0, 0), 127), x1c = min(max(x1, 0), 127);
      const int y0c = min(max(y0, 0), 127), y1c = min(max(y1, 0), 127);
      const float w00 = (vx0 && vy0) ? (1.f - wx) * (1.f - wy) : 0.f;
      const float w01 = (vx1 && vy0) ? wx * (1.f - wy) : 0.f;
      const float w10 = (vx0 && vy1) ? (1.f - wx) * wy : 0.f;
      const float w11 = (vx1 && vy1) ? wx * wy : 0.f;
      const long base = (long)ind[n] * (64L * 16384);
      const int a00 = y0c * 128 + x0c, a01 = y0c * 128 + x1c;
      const int a10 = y1c * 128 + x0c, a11 = y1c * 128 + x1c;
#pragma unroll
      for (int qq = 0; qq < 4; qq++) {
        ushort hh[4], ll[4];
#pragma unroll
        for (int cc = 0; cc < 4; cc++) {
          const int c = qg * 16 + qq * 4 + cc;
          const float* f = cnn + base + (long)c * 16384;
          float x = f[a00] * w00 + f[a01] * w01 + f[a10] * w10 + f[a11] * w11;
          split_bf(x, hh[cc], ll[cc]);
        }
        const int G = ((qg >> 1) * 4 + qq) ^ sw;
        char* a = xb + p * 512 + G * 16 + (qg & 1) * 8;
        *(uint2*)a = make_uint2((uint)hh[0] | ((uint)hh[1] << 16), (uint)hh[2] | ((uint)hh[3] << 16));
        *(uint2*)(a + 256) = make_uint2((uint)ll[0] | ((uint)ll[1] << 16), (uint)ll[2] | ((uint)ll[3] << 16));
      }
    } else {
#pragma unroll
      for (int qq = 0; qq < 4; qq++) {
        ushort hh[4], ll[4];
        if (qg == 4 && qq == 0) {
          float v0 = c_it[nb * 2 + 0] * 4.f, v1 = c_it[nb * 2 + 1] * 4.f, v2 = cls_in[nb];
          split_bf(v0, hh[0], ll[0]); split_bf(v1, hh[1], ll[1]); split_bf(v2, hh[2], ll[2]);
          hh[3] = 0; ll[3] = 0;
        } else {
          hh[0] = hh[1] = hh[2] = hh[3] = 0; ll[0] = ll[1] = ll[2] = ll[3] = 0;
        }
        const int G = ((qg >> 1) * 4 + qq) ^ sw;
        char* a = xb + p * 512 + G * 16 + (qg & 1) * 8;
        *(uint2*)a = make_uint2((uint)hh[0] | ((uint)hh[1] << 16), (uint)hh[2] | ((uint)hh[3] << 16));
        *(uint2*)(a + 256) = make_uint2((uint)ll[0] | ((uint)ll[1] << 16), (uint)ll[2] | ((uint)ll[3] << 16));
      }
    }
  }
  __syncthreads();

  const f32x4 fz = {0.f, 0.f, 0.f, 0.f};
  // G accumulator: rows wv*48 + f*16 + g*4 + e (0..767: <256 fusion, >=256 h1), pos nt*16+li
  f32x4 acc[3][8];
#pragma unroll
  for (int f = 0; f < 3; f++)
#pragma unroll
    for (int c = 0; c < 8; c++) acc[f][c] = fz;

  const uint4* caw = (const uint4*)CAW;
  const uint4* gaw = (const uint4*)GW;

  for (int l = 0; l < 8; l++) {
    const int dil = (l >= 6) ? 4 : ((l >= 4) ? 2 : 1);
    const int nic = (l == 0) ? 3 : 4;
    // ======== READ REGION: G-update(l-1) + conv(l), both read xt = x_{l-1} ========
    if (l > 0) {
      const uint4* gwl = gaw + ((long)((l - 1) * 16 + wv)) * 1536 + lane;
#pragma unroll
      for (int ic = 0; ic < 4; ic++) {
        const uint4* w0 = gwl + (0 * 4 + ic) * 128;
        const uint4* w1 = gwl + (1 * 4 + ic) * 128;
        const uint4* w2p = gwl + (2 * 4 + ic) * 128;
        const bf16x8 Ah0 = asb(w0[0]), Al0 = asb(w0[64]);
        const bf16x8 Ah1 = asb(w1[0]), Al1 = asb(w1[64]);
        const bf16x8 Ah2 = asb(w2p[0]), Al2 = asb(w2p[64]);
#pragma unroll
        for (int nt = 0; nt < 8; nt++) {
          const int pc = nt * 16 + li;
          bf16x8 bh, bl;
          read_frag_pair(xb, pc, g, ic, bh, bl);
          acc[0][nt] = MFMA_(Ah0, bh, acc[0][nt]);
          acc[1][nt] = MFMA_(Ah1, bh, acc[1][nt]);
          acc[2][nt] = MFMA_(Ah2, bh, acc[2][nt]);
          acc[0][nt] = MFMA_(Ah0, bl, acc[0][nt]);
          acc[1][nt] = MFMA_(Ah1, bl, acc[1][nt]);
          acc[2][nt] = MFMA_(Ah2, bl, acc[2][nt]);
          acc[0][nt] = MFMA_(Al0, bh, acc[0][nt]);
          acc[1][nt] = MFMA_(Al1, bh, acc[1][nt]);
          acc[2][nt] = MFMA_(Al2, bh, acc[2][nt]);
        }
      }
    }
    // conv(l)
    f32x4 cacc[2][2];
    cacc[0][0] = fz; cacc[0][1] = fz; cacc[1][0] = fz; cacc[1][1] = fz;
    const uint4* cawl = caw + ((long)(l * 4 + mp)) * 9216;
    for (int tap = 0; tap < 9; tap++) {
      const int shift = (tap - 4) * dil;
      const int pc0 = (np * 32 + li + shift + 128) & 127;
      const int pc1 = (np * 32 + 16 + li + shift + 128) & 127;
      const uint4* cawt = cawl + tap * 1024 + lane;
      for (int ic = 0; ic < nic; ic++) {
        const uint4* w0 = cawt + ic * 256;
        const bf16x8 Ah0 = asb(w0[0]),   Ah1 = asb(w0[64]);
        const bf16x8 Al0 = asb(w0[128]), Al1 = asb(w0[192]);
        bf16x8 bh, bl;
        read_frag_pair(xb, pc0, g, ic, bh, bl);
        cacc[0][0] = MFMA_(Ah0, bh, cacc[0][0]);
        cacc[1][0] = MFMA_(Ah1, bh, cacc[1][0]);
        cacc[0][0] = MFMA_(Ah0, bl, cacc[0][0]);
        cacc[1][0] = MFMA_(Ah1, bl, cacc[1][0]);
        cacc[0][0] = MFMA_(Al0, bh, cacc[0][0]);
        cacc[1][0] = MFMA_(Al1, bh, cacc[1][0]);
        read_frag_pair(xb, pc1, g, ic, bh, bl);
        cacc[0][1] = MFMA_(Ah0, bh, cacc[0][1]);
        cacc[1][1] = MFMA_(Ah1, bh, cacc[1][1]);
        cacc[0][1] = MFMA_(Ah0, bl, cacc[0][1]);
        cacc[1][1] = MFMA_(Ah1, bl, cacc[1][1]);
        cacc[0][1] = MFMA_(Al0, bh, cacc[0][1]);
        cacc[1][1] = MFMA_(Al1, bh, cacc[1][1]);
      }
    }
    bar_lgkm();
    // ======== EPILOGUE: bias + relu + residual -> xt granules ========
    {
      const float* bsrc = (l == 0) ? head_b : (res_b + (l - 1) * 128);
      const float4 b0 = *(const float4*)&bsrc[mp * 32 + g * 4];
      const float4 b1 = *(const float4*)&bsrc[mp * 32 + 16 + g * 4];
#pragma unroll
      for (int nt = 0; nt < 2; nt++) {
        const int p = np * 32 + nt * 16 + li;
        const int X = (mp * 64 + g * 16) ^ ((p & 7) << 4);
        char* a = xb + p * 512 + X;
        float v[8];
        v[0] = fmaxf(cacc[0][nt][0] + b0.x, 0.f);
        v[1] = fmaxf(cacc[0][nt][1] + b0.y, 0.f);
        v[2] = fmaxf(cacc[0][nt][2] + b0.z, 0.f);
        v[3] = fmaxf(cacc[0][nt][3] + b0.w, 0.f);
        v[4] = fmaxf(cacc[1][nt][0] + b1.x, 0.f);
        v[5] = fmaxf(cacc[1][nt][1] + b1.y, 0.f);
        v[6] = fmaxf(cacc[1][nt][2] + b1.z, 0.f);
        v[7] = fmaxf(cacc[1][nt][3] + b1.w, 0.f);
        if (l > 0) {
          const uint4 oh = *(const uint4*)a;
          const uint4 ol = *(const uint4*)(a + 256);
          const uint hw[4] = {oh.x, oh.y, oh.z, oh.w};
          const uint lw[4] = {ol.x, ol.y, ol.z, ol.w};
#pragma unroll
          for (int k = 0; k < 8; k++) {
            const uint hh = (k & 1) ? (hw[k >> 1] & 0xFFFF0000u) : ((hw[k >> 1] & 0xFFFFu) << 16);
            const uint ll = (k & 1) ? (lw[k >> 1] & 0xFFFF0000u) : ((lw[k >> 1] & 0xFFFFu) << 16);
            v[k] += __uint_as_float(hh) + __uint_as_float(ll);
          }
        }
        ushort hh[8], ll[8];
#pragma unroll
        for (int k = 0; k < 8; k++) split_bf(v[k], hh[k], ll[k]);
        *(uint4*)a = make_uint4((uint)hh[0] | ((uint)hh[1] << 16), (uint)hh[2] | ((uint)hh[3] << 16),
                                (uint)hh[4] | ((uint)hh[5] << 16), (uint)hh[6] | ((uint)hh[7] << 16));
        *(uint4*)(a + 256) = make_uint4((uint)ll[0] | ((uint)ll[1] << 16), (uint)ll[2] | ((uint)ll[3] << 16),
                                        (uint)ll[4] | ((uint)ll[5] << 16), (uint)ll[6] | ((uint)ll[7] << 16));
      }
    }
    __syncthreads();
  }

  // ======== tail G-update on x_7 (still in xt) ========
  {
    const uint4* gwl = gaw + ((long)(7 * 16 + wv)) * 1536 + lane;
#pragma unroll
    for (int ic = 0; ic < 4; ic++) {
      const uint4* w0 = gwl + (0 * 4 + ic) * 128;
      const uint4* w1 = gwl + (1 * 4 + ic) * 128;
      const uint4* w2p = gwl + (2 * 4 + ic) * 128;
      const bf16x8 Ah0 = asb(w0[0]), Al0 = asb(w0[64]);
      const bf16x8 Ah1 = asb(w1[0]), Al1 = asb(w1[64]);
      const bf16x8 Ah2 = asb(w2p[0]), Al2 = asb(w2p[64]);
#pragma unroll
      for (int nt = 0; nt < 8; nt++) {
        const int pc = nt * 16 + li;
        bf16x8 bh, bl;
        read_frag_pair(xb, pc, g, ic, bh, bl);
        acc[0][nt] = MFMA_(Ah0, bh, acc[0][nt]);
        acc[1][nt] = MFMA_(Ah1, bh, acc[1][nt]);
        acc[2][nt] = MFMA_(Ah2, bh, acc[2][nt]);
        acc[0][nt] = MFMA_(Ah0, bl, acc[0][nt]);
        acc[1][nt] = MFMA_(Ah1, bl, acc[1][nt]);
        acc[2][nt] = MFMA_(Ah2, bl, acc[2][nt]);
        acc[0][nt] = MFMA_(Al0, bh, acc[0][nt]);
        acc[1][nt] = MFMA_(Al1, bh, acc[1][nt]);
        acc[2][nt] = MFMA_(Al2, bh, acc[2][nt]);
      }
    }
  }

  // ---- fusion rows (<256): max over all 128 positions -> scr ----
#pragma unroll
  for (int f = 0; f < 3; f++) {
    const int base = wv * 48 + f * 16;
    if (base < 256) {
#pragma unroll
      for (int e = 0; e < 4; e++) {
        float m = acc[f][0][e];
#pragma unroll
        for (int nt = 1; nt < 8; nt++) m = fmaxf(m, acc[f][nt][e]);
#pragma unroll
        for (int s = 1; s < 16; s <<= 1) m = fmaxf(m, __shfl_xor(m, s, 64));
        if (li == 0) scr[base + g * 4 + e] = m;
      }
    }
  }
  bar_lgkm();
  if (t < 256) sg[t] = scr[t] + fus_b[t];
  bar_lgkm();

  // ---- hg[512] = bias + W1G^T (sg) ----
  if (t < 512) {
    float s = (t < 256) ? p1b[t] : c1b[t - 256];
    const float* w = W1G + t;
#pragma unroll 8
    for (int c = 0; c < 256; c++) s = fmaf(w[(long)c * 512], sg[c], s);
    hg_s[t] = s;
  }
  bar_lgkm();

  // ---- h1 rows (>=256): bias + relu in regs ----
#pragma unroll
  for (int f = 0; f < 3; f++) {
    const int base = wv * 48 + f * 16;
    if (base >= 256) {
      const float4 hq = *(const float4*)&hg_s[base - 256 + g * 4];
#pragma unroll
      for (int nt = 0; nt < 8; nt++) {
        acc[f][nt][0] = fmaxf(acc[f][nt][0] + hq.x, 0.f);
        acc[f][nt][1] = fmaxf(acc[f][nt][1] + hq.y, 0.f);
        acc[f][nt][2] = fmaxf(acc[f][nt][2] + hq.z, 0.f);
        acc[f][nt][3] = fmaxf(acc[f][nt][3] + hq.w, 0.f);
      }
    }
  }

  // ---- phase C: h2 = relu(W2 @ h1 + b2), 4 pos-quarters via K=512 granule image in xt ----
  // quarter image: pos pl (32 rows of 2 KB): hi granule at pl*2048 + ((kc*64+gp*16)^((pl&7)<<4)) + half*8, lo +1024
  // NOTE: q loop MUST be unrolled — acc[f][2*q+ntl] with runtime q demotes acc to scratch (rule #20).
  const uint4* w2 = (const uint4*)W2F;
  f32x4 a2q[4];
#pragma unroll
  for (int q = 0; q < 4; q++) {
    a2q[q] = fz;
    // stage h1 cells for nt in {2q, 2q+1}
#pragma unroll
    for (int f = 0; f < 3; f++) {
      const int base = wv * 48 + f * 16;
      if (base >= 256) {
        const int r1b = base - 256 + g * 4;      // 4-aligned k-index of elems e=0..3
        const int kc = r1b >> 5;
        const int kic = r1b & 31;
        const int gp = (kic & 15) >> 2;
        const int half = kic >> 4;
#pragma unroll
        for (int ntl = 0; ntl < 2; ntl++) {
          const int nt = 2 * q + ntl;
          const int pl = ntl * 16 + li;
          char* a = xb + pl * 2048 + ((kc * 64 + gp * 16) ^ ((pl & 7) << 4)) + half * 8;
          ushort hh[4], ll[4];
          split_bf(acc[f][nt][0], hh[0], ll[0]);
          split_bf(acc[f][nt][1], hh[1], ll[1]);
          split_bf(acc[f][nt][2], hh[2], ll[2]);
          split_bf(acc[f][nt][3], hh[3], ll[3]);
          *(uint2*)a = make_uint2((uint)hh[0] | ((uint)hh[1] << 16), (uint)hh[2] | ((uint)hh[3] << 16));
          *(uint2*)(a + 1024) = make_uint2((uint)ll[0] | ((uint)ll[1] << 16), (uint)ll[2] | ((uint)ll[3] << 16));
        }
      }
    }
    bar_lgkm();
    // read: out-row frag mw (0..3 pred2, 4..7 cls2); pos pl = qw*16 + li
    {
      const int blkc = mw >> 2;
      const int pl = qw * 16 + li;
#pragma unroll
      for (int ic8 = 0; ic8 < 8; ic8++) {
        const int kc = blkc * 8 + ic8;
        const uint4* wb = w2 + (((long)(blkc * 4 + (mw & 3)) * 8 + ic8) * 2) * 64 + lane;
        const bf16x8 Ah = asb(wb[0]), Al = asb(wb[64]);
        const char* ba = xb + pl * 2048 + ((kc * 64 + g * 16) ^ ((pl & 7) << 4));
        const bf16x8 bh = asb(*(const uint4*)ba);
        const bf16x8 bl = asb(*(const uint4*)(ba + 1024));
        a2q[q] = MFMA_(Ah, bh, a2q[q]);
        a2q[q] = MFMA_(Ah, bl, a2q[q]);
        a2q[q] = MFMA_(Al, bh, a2q[q]);
      }
    }
    bar_lgkm();   // reads done before next quarter's writers overwrite
  }

  // ---- h2 -> LDS floats (overwrite xt) ----
  {
    float* h2L = (float*)xb;
#pragma unroll
    for (int q = 0; q < 4; q++) {
#pragma unroll
      for (int e = 0; e < 4; e++) {
        const int row = mw * 16 + g * 4 + e;
        const float bb = (mw < 4) ? p2b[row] : c2b[row - 64];
        h2L[row * 128 + q * 32 + qw * 16 + li] = fmaxf(a2q[q][e] + bb, 0.f);
      }
    }
  }
  bar_lgkm();

  // ---- tail: pred3/cls3 + outputs + NMS ----
  {
    const float* h2L = (const float*)xb;
    float sig = 0.f;
    const int pp = t & 127;
    if (t < 128) {
      float o0v = p3b[0], o1v = p3b[1], cv = c3b[0];
      for (int j = 0; j < 64; j++) {
        const float hp = h2L[j * 128 + pp];
        const float hc = h2L[(64 + j) * 128 + pp];
        o0v = fmaf(p3w[j], hp, o0v);
        o1v = fmaf(p3w[64 + j], hp, o1v);
        cv = fmaf(c3w[j], hc, cv);
      }
      const long ip = ((long)n * 128 + pp) * 2;
      out[ip + 0] = i_it[ip + 0] * 4.f + o0v;
      out[ip + 1] = i_it[ip + 1] * 4.f + o1v;
      out[131072 + (long)n * 128 + pp] = cv;
      sig = 1.f / (1.f + expf(-cv));
      scr[pp] = sig;
    }
    bar_lgkm();
    if (t < 128) {
      float m = scr[pp];
#pragma unroll
      for (int s = 1; s <= 2; s++) {
        m = fmaxf(m, scr[(pp + s) & 127]);
        m = fmaxf(m, scr[(pp + 128 - s) & 127]);
      }
      out[196608 + (long)n * 128 + pp] = (sig >= m) ? sig : 0.f;
    }
  }
}

extern "C" void kernel_launch(void* const* d_in, const int* in_sizes, int n_in,
                              void* d_out, int out_size, void* d_ws, size_t ws_size,
                              hipStream_t stream) {
  const float* cnn      = (const float*)d_in[0];
  const float* i_it     = (const float*)d_in[1];
  const float* c_it     = (const float*)d_in[2];
  const float* it_cls   = (const float*)d_in[3];
  const int*   ind      = (const int*)d_in[4];
  const float* head_w   = (const float*)d_in[5];
  const float* head_b   = (const float*)d_in[6];
  const float* res_w    = (const float*)d_in[7];
  const float* res_b    = (const float*)d_in[8];
  const float* fusion_w = (const float*)d_in[9];
  const float* fusion_b = (const float*)d_in[10];
  const float* pred1_w  = (const float*)d_in[11];
  const float* pred1_b  = (const float*)d_in[12];
  const float* pred2_w  = (const float*)d_in[13];
  const float* pred2_b  = (const float*)d_in[14];
  const float* pred3_w  = (const float*)d_in[15];
  const float* pred3_b  = (const float*)d_in[16];
  const float* cls1_w   = (const float*)d_in[17];
  const float* cls1_b   = (const float*)d_in[18];
  const float* cls2_w   = (const float*)d_in[19];
  const float* cls2_b   = (const float*)d_in[20];
  const float* cls3_w   = (const float*)d_in[21];
  const float* cls3_b   = (const float*)d_in[22];
  float* ws = (float*)d_ws;
  float* out = (float*)d_out;
  const ushort* wsu = (const ushort*)d_ws;

  k_repack<<<(int)((REPACK_N + 255) / 256), 256, 0, stream>>>(
      head_w, res_w, fusion_w, pred1_w, cls1_w, pred2_w, cls2_w, ws);

  k_fused<<<512, 1024, 0, stream>>>(cnn, i_it, c_it, it_cls, ind,
                                    wsu + UOFF_CAW, wsu + UOFF_GW, wsu + UOFF_W2F,
                                    head_b, res_b, fusion_b, ws + OFF_W1G,
                                    pred1_b, cls1_b, pred2_b, cls2_b,
                                    pred3_w, pred3_b, cls3_w, cls3_b, out);
}

// Round 9
// 1021.788 us; speedup vs baseline: 1.3389x; 1.3013x over previous
//
#include <hip/hip_runtime.h>
#include <math.h>

typedef __attribute__((ext_vector_type(8))) short bf16x8;
typedef __attribute__((ext_vector_type(4))) float f32x4;

// ---------------- workspace layout ----------------
// ushort region (bf16 packed weights), offsets in ushorts:
#define UOFF_CAW 0L        // conv A  [l8][mp4][tap9][ic4][split2][mt2][lane64][e8] = 2359296 bf16
#define UOFF_FAW 2359296L  // fusion A [l8][fm2 8][ic4][split2][mt2][lane64][e8]   =  524288 bf16
#define UOFF_H1W 2883584L  // h1 A [blk2][mp8][slab8][ic4][split2][mt2][lane64][e8]= 1048576 bf16
#define UOFF_W2F 3932160L  // pred2/cls2 A [blk2][mfr4][ic8][split2][lane64][e8]   =   65536 bf16
#define NB_TOT   3997696L  // total bf16 elems (= 1998848 floats)
// float region, offsets in floats:
#define OFF_W1G  1998848L  // [c256][o512] = 131072
#define OFF_GRAW 2129920L  // [512][256] = 131072
#define OFF_DYN  2260992L  // dynamic: states (granule images, 131072 f/poly)
#define REPACK_N 4128768L  // NB_TOT + 131072

// ---------------- helpers ----------------
__device__ inline ushort f2bf_rne(float x) {
  uint u = __float_as_uint(x);
  return (ushort)((u + 0x7FFFu + ((u >> 16) & 1u)) >> 16);
}
__device__ inline void split_bf(float x, ushort& h, ushort& l) {
  uint u = __float_as_uint(x);
  uint hb = (u + 0x7FFFu + ((u >> 16) & 1u)) & 0xFFFF0000u;
  h = (ushort)(hb >> 16);
  l = f2bf_rne(x - __uint_as_float(hb));
}
__device__ inline ushort bfsel(float w, int split) {
  uint u = __float_as_uint(w);
  uint hb = (u + 0x7FFFu + ((u >> 16) & 1u)) & 0xFFFF0000u;
  if (split == 0) return (ushort)(hb >> 16);
  float lo = w - __uint_as_float(hb);
  uint ul = __float_as_uint(lo);
  return (ushort)((ul + 0x7FFFu + ((ul >> 16) & 1u)) >> 16);
}
__device__ inline bf16x8 asb(uint4 a) {
  union { uint4 u; bf16x8 v; } x; x.u = a; return x.v;
}
__device__ inline f32x4 MFMA_(bf16x8 a, bf16x8 b, f32x4 c) {
  return __builtin_amdgcn_mfma_f32_16x16x32_bf16(a, b, c, 0, 0, 0);
}
// lgkm-only barrier: does NOT drain vmcnt (weight loads / states stores stay in flight).
__device__ inline void bar_lgkm() {
  asm volatile("s_waitcnt lgkmcnt(0)" ::: "memory");
  __builtin_amdgcn_s_barrier();
}

// Conv-image LDS layout (64 KB): per position p (128 rows of 512 B), 16 hi-granules (16 B) + 16 lo.
// Granule (ic,g) holds bf16 of ch ic*32 + {4g..4g+3, 16+4g..16+4g+3} at byte (ic*64+g*16) ^ ((p&7)<<4);
// lo-plane at +256 B.
__device__ inline void read_frag_pair(const char* xb, int pc, int g, int ic,
                                      bf16x8& bh, bf16x8& bl) {
  const int s0 = (pc & 7) << 4;
  const char* a = xb + pc * 512 + (((ic * 64 + (g << 4))) ^ s0);
  bh = asb(*(const uint4*)a);
  bl = asb(*(const uint4*)(a + 256));
}

// ---------------- repack ----------------
__global__ void k_repack(const float* __restrict__ head_w, const float* __restrict__ res_w,
                         const float* __restrict__ fusion_w,
                         const float* __restrict__ pred1_w, const float* __restrict__ cls1_w,
                         const float* __restrict__ pred2_w, const float* __restrict__ cls2_w,
                         float* __restrict__ ws) {
  const long j = (long)blockIdx.x * 256 + threadIdx.x;
  if (j >= REPACK_N) return;
  if (j < NB_TOT) {
    ushort* wsu = (ushort*)ws;
    float w;
    if (j < UOFF_FAW) {                       // CAW
      int e = (int)(j & 7); long q = j >> 3;
      int lane = (int)(q & 63); q >>= 6;
      int mt = (int)(q & 1); q >>= 1;
      int split = (int)(q & 1); q >>= 1;
      int ic = (int)(q & 3); q >>= 2;
      int tap = (int)(q % 9); q /= 9;
      int mp = (int)(q & 3); int l = (int)(q >> 2);
      int gg = lane >> 4;
      int kl = (e < 4) ? (4 * gg + e) : (16 + 4 * gg + e - 4);
      int m = mp * 32 + mt * 16 + (lane & 15);
      int i = ic * 32 + kl;
      if (l == 0) w = (i < 67) ? head_w[((long)m * 67 + i) * 9 + tap] : 0.f;
      else        w = res_w[(((long)(l - 1) * 128 + m) * 128 + i) * 9 + tap];
      wsu[j] = bfsel(w, split);
    } else if (j < UOFF_H1W) {                // FAW
      long jj = j - UOFF_FAW;
      int e = (int)(jj & 7); long q = jj >> 3;
      int lane = (int)(q & 63); q >>= 6;
      int mt = (int)(q & 1); q >>= 1;
      int split = (int)(q & 1); q >>= 1;
      int ic = (int)(q & 3); q >>= 2;
      int fm2 = (int)(q & 7); int l = (int)(q >> 3);
      int gg = lane >> 4;
      int kl = (e < 4) ? (4 * gg + e) : (16 + 4 * gg + e - 4);
      int m = fm2 * 32 + mt * 16 + (lane & 15);
      int i = ic * 32 + kl;
      w = fusion_w[(long)m * 1024 + l * 128 + i];
      wsu[j] = bfsel(w, split);
    } else if (j < UOFF_W2F) {                // H1W
      long jj = j - UOFF_H1W;
      int e = (int)(jj & 7); long q = jj >> 3;
      int lane = (int)(q & 63); q >>= 6;
      int mt = (int)(q & 1); q >>= 1;
      int split = (int)(q & 1); q >>= 1;
      int ic = (int)(q & 3); q >>= 2;
      int slab = (int)(q & 7); q >>= 3;
      int mp = (int)(q & 7); int blk = (int)(q >> 3);
      int gg = lane >> 4;
      int kl = (e < 4) ? (4 * gg + e) : (16 + 4 * gg + e - 4);
      int m = blk * 256 + mp * 32 + mt * 16 + (lane & 15);
      int k = slab * 128 + ic * 32 + kl;
      w = (m < 256) ? pred1_w[(long)m * 1280 + 256 + k] : cls1_w[(long)(m - 256) * 1280 + 256 + k];
      wsu[j] = bfsel(w, split);
    } else {                                  // W2F (pred2/cls2 A-fragments)
      long jj = j - UOFF_W2F;
      int e = (int)(jj & 7); long q = jj >> 3;
      int lane = (int)(q & 63); q >>= 6;
      int split = (int)(q & 1); q >>= 1;
      int ic = (int)(q & 7); q >>= 3;
      int mfr = (int)(q & 3); int blk = (int)(q >> 2);
      int gg = lane >> 4;
      int kl = (e < 4) ? (4 * gg + e) : (16 + 4 * gg + e - 4);
      int m = mfr * 16 + (lane & 15);
      int k = ic * 32 + kl;
      w = blk ? cls2_w[(long)m * 256 + k] : pred2_w[(long)m * 256 + k];
      wsu[j] = bfsel(w, split);
    }
  } else {                                    // W1G (fp32)
    long q = j - NB_TOT; int o = (int)(q & 511); int c = (int)(q >> 9);
    ws[OFF_W1G + q] = (o < 256) ? pred1_w[(long)o * 1280 + c] : cls1_w[(long)(o - 256) * 1280 + c];
  }
}

// ================ K1: gather + 8-layer conv chain (MFMA, M=32xN=32 per wave) ================
__global__ __launch_bounds__(1024) __attribute__((amdgpu_waves_per_eu(4)))
void k_conv(const float* __restrict__ cnn, const float* __restrict__ i_it,
            const float* __restrict__ c_it, const float* __restrict__ cls_in,
            const int* __restrict__ ind,
            const ushort* __restrict__ CAW, const ushort* __restrict__ FAW,
            const float* __restrict__ head_b, const float* __restrict__ res_b,
            float* __restrict__ graw, float* __restrict__ states, int p0) {
  __shared__ uint4 xt4[4096];   // 64 KB granule image
  __shared__ float scr[512];
  char* xb = (char*)xt4;
  const int ln = blockIdx.x, n = p0 + ln, t = threadIdx.x;
  const int lane = t & 63, li = lane & 15, g = lane >> 4;
  const int wv = __builtin_amdgcn_readfirstlane(t >> 6);
  const int mp = wv & 3, np = wv >> 2;     // conv: M=32 ch x N=32 pos per wave
  const int fm2 = wv & 7, fq = wv >> 3;    // fusion: M=32 of 256 x N=64 pos per wave

  // ---- bilinear gather -> LDS fragment granules ----
  {
    const int p = t & 127, qg = t >> 7;
    const long nb = (long)n * 128 + p;
    const int sw = p & 7;
    if (qg < 4) {
      const float gx = i_it[nb * 2 + 0] - 0.5f;
      const float gy = i_it[nb * 2 + 1] - 0.5f;
      const float fx = floorf(gx), fy = floorf(gy);
      const float wx = gx - fx, wy = gy - fy;
      const int x0 = (int)fx, y0 = (int)fy, x1 = x0 + 1, y1 = y0 + 1;
      const bool vx0 = (x0 >= 0) & (x0 < 128), vx1 = (x1 >= 0) & (x1 < 128);
      const bool vy0 = (y0 >= 0) & (y0 < 128), vy1 = (y1 >= 0) & (y1 < 128);
      const int x0c = min(max(x0, 0), 127), x1c = min(max(x1, 0), 127);
      const int y0c = min(max(y0, 0), 127), y1c = min(max(y1, 0), 127);
      const float w00 = (vx0 && vy0) ? (1.f - wx) * (1.f - wy) : 0.f;
      const float w01 = (vx1 && vy0) ? wx * (1.f - wy) : 0.f;
      const float w10 = (vx0 && vy1) ? (1.f - wx) * wy : 0.f;
      const float w11 = (vx1 && vy1) ? wx * wy : 0.f;
      const long base = (long)ind[n] * (64L * 16384);
      const int a00 = y0c * 128 + x0c, a01 = y0c * 128 + x1c;
      const int a10 = y1c * 128 + x0c, a11 = y1c * 128 + x1c;
#pragma unroll
      for (int qq = 0; qq < 4; qq++) {
        ushort hh[4], ll[4];
#pragma unroll
        for (int cc = 0; cc < 4; cc++) {
          const int c = qg * 16 + qq * 4 + cc;
          const float* f = cnn + base + (long)c * 16384;
          float x = f[a00] * w00 + f[a01] * w01 + f[a10] * w10 + f[a11] * w11;
          split_bf(x, hh[cc], ll[cc]);
        }
        const int G = ((qg >> 1) * 4 + qq) ^ sw;
        char* a = xb + p * 512 + G * 16 + (qg & 1) * 8;
        *(uint2*)a = make_uint2((uint)hh[0] | ((uint)hh[1] << 16), (uint)hh[2] | ((uint)hh[3] << 16));
        *(uint2*)(a + 256) = make_uint2((uint)ll[0] | ((uint)ll[1] << 16), (uint)ll[2] | ((uint)ll[3] << 16));
      }
    } else {
#pragma unroll
      for (int qq = 0; qq < 4; qq++) {
        ushort hh[4], ll[4];
        if (qg == 4 && qq == 0) {
          float v0 = c_it[nb * 2 + 0] * 4.f, v1 = c_it[nb * 2 + 1] * 4.f, v2 = cls_in[nb];
          split_bf(v0, hh[0], ll[0]); split_bf(v1, hh[1], ll[1]); split_bf(v2, hh[2], ll[2]);
          hh[3] = 0; ll[3] = 0;
        } else {
          hh[0] = hh[1] = hh[2] = hh[3] = 0; ll[0] = ll[1] = ll[2] = ll[3] = 0;
        }
        const int G = ((qg >> 1) * 4 + qq) ^ sw;
        char* a = xb + p * 512 + G * 16 + (qg & 1) * 8;
        *(uint2*)a = make_uint2((uint)hh[0] | ((uint)hh[1] << 16), (uint)hh[2] | ((uint)hh[3] << 16));
        *(uint2*)(a + 256) = make_uint2((uint)ll[0] | ((uint)ll[1] << 16), (uint)ll[2] | ((uint)ll[3] << 16));
      }
    }
  }
  __syncthreads();

  const f32x4 fz = {0.f, 0.f, 0.f, 0.f};
  f32x4 facc[2][4];
#pragma unroll
  for (int a = 0; a < 2; a++)
#pragma unroll
    for (int b = 0; b < 4; b++) facc[a][b] = fz;

  const uint4* caw = (const uint4*)CAW;
  const uint4* faw = (const uint4*)FAW;
  uint4* stq = (uint4*)(states + (long)ln * 131072);

  for (int l = 0; l < 8; l++) {
    const int dil = (l >= 6) ? 4 : ((l >= 4) ? 2 : 1);
    const int nic = (l == 0) ? 3 : 4;
    // ======== READ REGION: copy(l-1) + fusion(l-1) + conv(l), all read xt ========
    if (l > 0) {
      uint4* dst = stq + (long)(l - 1) * 4096;
#pragma unroll
      for (int k = 0; k < 4; k++) dst[k * 1024 + t] = xt4[k * 1024 + t];
      const uint4* fawl = faw + ((long)((l - 1) * 8 + fm2)) * 1024 + lane;
#pragma unroll
      for (int ic = 0; ic < 4; ic++) {
        const uint4* w0 = fawl + ic * 256;
        const bf16x8 Ah0 = asb(w0[0]),   Ah1 = asb(w0[64]);
        const bf16x8 Al0 = asb(w0[128]), Al1 = asb(w0[192]);
#pragma unroll
        for (int nt = 0; nt < 4; nt++) {
          const int pc = fq * 64 + nt * 16 + li;
          bf16x8 bh, bl;
          read_frag_pair(xb, pc, g, ic, bh, bl);
          facc[0][nt] = MFMA_(Ah0, bh, facc[0][nt]);
          facc[1][nt] = MFMA_(Ah1, bh, facc[1][nt]);
          facc[0][nt] = MFMA_(Ah0, bl, facc[0][nt]);
          facc[1][nt] = MFMA_(Ah1, bl, facc[1][nt]);
          facc[0][nt] = MFMA_(Al0, bh, facc[0][nt]);
          facc[1][nt] = MFMA_(Al1, bh, facc[1][nt]);
        }
      }
    }
    // conv(l)
    f32x4 cacc[2][2];
    cacc[0][0] = fz; cacc[0][1] = fz; cacc[1][0] = fz; cacc[1][1] = fz;
    const uint4* cawl = caw + ((long)(l * 4 + mp)) * 9216;
    for (int tap = 0; tap < 9; tap++) {
      const int shift = (tap - 4) * dil;
      const int pc0 = (np * 32 + li + shift + 128) & 127;
      const int pc1 = (np * 32 + 16 + li + shift + 128) & 127;
      const uint4* cawt = cawl + tap * 1024 + lane;
      for (int ic = 0; ic < nic; ic++) {
        bf16x8 bh0, bl0, bh1, bl1;
        read_frag_pair(xb, pc0, g, ic, bh0, bl0);
        read_frag_pair(xb, pc1, g, ic, bh1, bl1);
        const uint4* w0 = cawt + ic * 256;
        const bf16x8 Ah0 = asb(w0[0]),   Ah1 = asb(w0[64]);
        const bf16x8 Al0 = asb(w0[128]), Al1 = asb(w0[192]);
        cacc[0][0] = MFMA_(Ah0, bh0, cacc[0][0]);
        cacc[0][1] = MFMA_(Ah0, bh1, cacc[0][1]);
        cacc[1][0] = MFMA_(Ah1, bh0, cacc[1][0]);
        cacc[1][1] = MFMA_(Ah1, bh1, cacc[1][1]);
        cacc[0][0] = MFMA_(Ah0, bl0, cacc[0][0]);
        cacc[0][1] = MFMA_(Ah0, bl1, cacc[0][1]);
        cacc[1][0] = MFMA_(Ah1, bl0, cacc[1][0]);
        cacc[1][1] = MFMA_(Ah1, bl1, cacc[1][1]);
        cacc[0][0] = MFMA_(Al0, bh0, cacc[0][0]);
        cacc[0][1] = MFMA_(Al0, bh1, cacc[0][1]);
        cacc[1][0] = MFMA_(Al1, bh0, cacc[1][0]);
        cacc[1][1] = MFMA_(Al1, bh1, cacc[1][1]);
      }
    }
    bar_lgkm();
    // ======== EPILOGUE: bias + relu + residual -> xt granules ========
    {
      const float* bsrc = (l == 0) ? head_b : (res_b + (l - 1) * 128);
      const float4 b0 = *(const float4*)&bsrc[mp * 32 + g * 4];
      const float4 b1 = *(const float4*)&bsrc[mp * 32 + 16 + g * 4];
#pragma unroll
      for (int nt = 0; nt < 2; nt++) {
        const int p = np * 32 + nt * 16 + li;
        const int X = (mp * 64 + g * 16) ^ ((p & 7) << 4);
        char* a = xb + p * 512 + X;
        float v[8];
        v[0] = fmaxf(cacc[0][nt][0] + b0.x, 0.f);
        v[1] = fmaxf(cacc[0][nt][1] + b0.y, 0.f);
        v[2] = fmaxf(cacc[0][nt][2] + b0.z, 0.f);
        v[3] = fmaxf(cacc[0][nt][3] + b0.w, 0.f);
        v[4] = fmaxf(cacc[1][nt][0] + b1.x, 0.f);
        v[5] = fmaxf(cacc[1][nt][1] + b1.y, 0.f);
        v[6] = fmaxf(cacc[1][nt][2] + b1.z, 0.f);
        v[7] = fmaxf(cacc[1][nt][3] + b1.w, 0.f);
        if (l > 0) {
          const uint4 oh = *(const uint4*)a;
          const uint4 ol = *(const uint4*)(a + 256);
          const uint hw[4] = {oh.x, oh.y, oh.z, oh.w};
          const uint lw[4] = {ol.x, ol.y, ol.z, ol.w};
#pragma unroll
          for (int k = 0; k < 8; k++) {
            const uint hh = (k & 1) ? (hw[k >> 1] & 0xFFFF0000u) : ((hw[k >> 1] & 0xFFFFu) << 16);
            const uint ll = (k & 1) ? (lw[k >> 1] & 0xFFFF0000u) : ((lw[k >> 1] & 0xFFFFu) << 16);
            v[k] += __uint_as_float(hh) + __uint_as_float(ll);
          }
        }
        ushort hh[8], ll[8];
#pragma unroll
        for (int k = 0; k < 8; k++) split_bf(v[k], hh[k], ll[k]);
        *(uint4*)a = make_uint4((uint)hh[0] | ((uint)hh[1] << 16), (uint)hh[2] | ((uint)hh[3] << 16),
                                (uint)hh[4] | ((uint)hh[5] << 16), (uint)hh[6] | ((uint)hh[7] << 16));
        *(uint4*)(a + 256) = make_uint4((uint)ll[0] | ((uint)ll[1] << 16), (uint)ll[2] | ((uint)ll[3] << 16),
                                        (uint)ll[4] | ((uint)ll[5] << 16), (uint)ll[6] | ((uint)ll[7] << 16));
      }
    }
    __syncthreads();
  }

  // ======== tail: copy(7) + fusion(7) ========
  {
    uint4* dst = stq + 7L * 4096;
#pragma unroll
    for (int k = 0; k < 4; k++) dst[k * 1024 + t] = xt4[k * 1024 + t];
    const uint4* fawl = faw + ((long)(7 * 8 + fm2)) * 1024 + lane;
#pragma unroll
    for (int ic = 0; ic < 4; ic++) {
      const uint4* w0 = fawl + ic * 256;
      const bf16x8 Ah0 = asb(w0[0]),   Ah1 = asb(w0[64]);
      const bf16x8 Al0 = asb(w0[128]), Al1 = asb(w0[192]);
#pragma unroll
      for (int nt = 0; nt < 4; nt++) {
        const int pc = fq * 64 + nt * 16 + li;
        bf16x8 bh, bl;
        read_frag_pair(xb, pc, g, ic, bh, bl);
        facc[0][nt] = MFMA_(Ah0, bh, facc[0][nt]);
        facc[1][nt] = MFMA_(Ah1, bh, facc[1][nt]);
        facc[0][nt] = MFMA_(Ah0, bl, facc[0][nt]);
        facc[1][nt] = MFMA_(Ah1, bl, facc[1][nt]);
        facc[0][nt] = MFMA_(Al0, bh, facc[0][nt]);
        facc[1][nt] = MFMA_(Al1, bh, facc[1][nt]);
      }
    }
  }

  // ---- fusion row-max over 128 positions -> graw ----
#pragma unroll
  for (int mt = 0; mt < 2; mt++) {
#pragma unroll
    for (int r = 0; r < 4; r++) {
      float m = fmaxf(fmaxf(facc[mt][0][r], facc[mt][1][r]),
                      fmaxf(facc[mt][2][r], facc[mt][3][r]));
#pragma unroll
      for (int s = 1; s < 16; s <<= 1) m = fmaxf(m, __shfl_xor(m, s, 64));
      if (li == 0) scr[(fm2 * 32 + mt * 16 + g * 4 + r) * 2 + fq] = m;
    }
  }
  bar_lgkm();
  if (t < 256) graw[(long)n * 256 + t] = fmaxf(scr[2 * t], scr[2 * t + 1]);
}

// =============== K2: hg + h1 + pred2/cls2 + pred3/cls3 + NMS fused; h1,h2 never leave the CU ===============
__global__ __launch_bounds__(1024) __attribute__((amdgpu_waves_per_eu(4)))
void k_h1t(const float* __restrict__ states, const ushort* __restrict__ H1W,
           const ushort* __restrict__ W2F,
           const float* __restrict__ graw, const float* __restrict__ fus_b,
           const float* __restrict__ W1G, const float* __restrict__ p1b, const float* __restrict__ c1b,
           const float* __restrict__ p2b, const float* __restrict__ c2b,
           const float* __restrict__ p3w, const float* __restrict__ p3b,
           const float* __restrict__ c3w, const float* __restrict__ c3b,
           const float* __restrict__ i_it, float* __restrict__ out, int p0) {
  __shared__ uint4 xt4[4096];   // 64 KB: slab staging, then h1 granule halves, then h2 floats
  __shared__ float sg[256];
  __shared__ float hg_s[256];
  char* xb = (char*)xt4;
  const int b = blockIdx.x, ln = b >> 1, blk = b & 1, t = threadIdx.x;
  const int n = p0 + ln;
  const int lane = t & 63, li = lane & 15, g = lane >> 4;
  const int wv = __builtin_amdgcn_readfirstlane(t >> 6);
  const int mw = wv & 7, qw = wv >> 3;     // phase B: M=32 of 256 x N=64 pos
  const uint4* sp = (const uint4*)(states + (long)ln * 131072);
  const uint4* aw = (const uint4*)H1W;
  const uint4* w2 = (const uint4*)W2F;
  const f32x4 fz = {0.f, 0.f, 0.f, 0.f};

  uint4 stg[4];
#pragma unroll
  for (int k = 0; k < 4; k++) stg[k] = sp[k * 1024 + t];

  // ---- phase A: hg for this block's 256 rows ----
  if (t < 256) sg[t] = graw[(long)n * 256 + t] + fus_b[t];
  __syncthreads();
  if (t < 256) {
    float s = blk ? c1b[t] : p1b[t];
    const float* w = W1G + blk * 256 + t;
#pragma unroll 8
    for (int c = 0; c < 256; c++) s = fmaf(w[(long)c * 512], sg[c], s);
    hg_s[t] = s;
  }

  // ---- phase B: h1 = W1H @ states (acc in regs) ----
  f32x4 acc[2][4];
#pragma unroll
  for (int a = 0; a < 2; a++)
#pragma unroll
    for (int c = 0; c < 4; c++) acc[a][c] = fz;

  for (int s = 0; s < 8; s++) {
#pragma unroll
    for (int k = 0; k < 4; k++) xt4[k * 1024 + t] = stg[k];
    bar_lgkm();
    if (s < 7) {
#pragma unroll
      for (int k = 0; k < 4; k++) stg[k] = sp[(s + 1) * 4096 + k * 1024 + t];
    }
    const uint4* awl = aw + (((long)(blk * 8 + mw)) * 8 + s) * 1024 + lane;
#pragma unroll
    for (int ic = 0; ic < 4; ic++) {
      const uint4* w0 = awl + ic * 256;
      const bf16x8 Ah0 = asb(w0[0]),   Ah1 = asb(w0[64]);
      const bf16x8 Al0 = asb(w0[128]), Al1 = asb(w0[192]);
#pragma unroll
      for (int nt = 0; nt < 4; nt++) {
        const int pc = qw * 64 + nt * 16 + li;
        bf16x8 bh, bl;
        read_frag_pair(xb, pc, g, ic, bh, bl);
        acc[0][nt] = MFMA_(Ah0, bh, acc[0][nt]);
        acc[1][nt] = MFMA_(Ah1, bh, acc[1][nt]);
        acc[0][nt] = MFMA_(Ah0, bl, acc[0][nt]);
        acc[1][nt] = MFMA_(Ah1, bl, acc[1][nt]);
        acc[0][nt] = MFMA_(Al0, bh, acc[0][nt]);
        acc[1][nt] = MFMA_(Al1, bh, acc[1][nt]);
      }
    }
    bar_lgkm();
  }

  // bias + relu in regs: rows (local) mw*32 + mt*16 + g*4 + e, pos qw*64 + nt*16 + li
  const float4 hq0 = *(const float4*)&hg_s[mw * 32 + g * 4];
  const float4 hq1 = *(const float4*)&hg_s[mw * 32 + 16 + g * 4];
#pragma unroll
  for (int nt = 0; nt < 4; nt++) {
    acc[0][nt][0] = fmaxf(acc[0][nt][0] + hq0.x, 0.f);
    acc[0][nt][1] = fmaxf(acc[0][nt][1] + hq0.y, 0.f);
    acc[0][nt][2] = fmaxf(acc[0][nt][2] + hq0.z, 0.f);
    acc[0][nt][3] = fmaxf(acc[0][nt][3] + hq0.w, 0.f);
    acc[1][nt][0] = fmaxf(acc[1][nt][0] + hq1.x, 0.f);
    acc[1][nt][1] = fmaxf(acc[1][nt][1] + hq1.y, 0.f);
    acc[1][nt][2] = fmaxf(acc[1][nt][2] + hq1.z, 0.f);
    acc[1][nt][3] = fmaxf(acc[1][nt][3] + hq1.w, 0.f);
  }

  // ---- phase C: h2 = W2 @ h1, per pos-half via LDS granules; results held in regs (a2s) ----
  // h1-granule image per half: pos pl (64 rows of 1 KB): hi granule (ic,g) at pl*1024 + (ic*64+g*16)^((pl&7)<<4), lo +512.
  const int mfr = wv & 3, nfr = wv >> 2;
  const float* b2 = blk ? c2b : p2b;
  f32x4 a2s[2];
#pragma unroll
  for (int h = 0; h < 2; h++) {
    bar_lgkm();
    if (qw == h) {
#pragma unroll
      for (int nt = 0; nt < 4; nt++) {
        const int pl = nt * 16 + li;
        char* a = xb + pl * 1024 + ((mw * 64 + g * 16) ^ ((pl & 7) << 4));
        ushort hh[8], ll[8];
#pragma unroll
        for (int e = 0; e < 4; e++) { split_bf(acc[0][nt][e], hh[e], ll[e]); }
#pragma unroll
        for (int e = 0; e < 4; e++) { split_bf(acc[1][nt][e], hh[4 + e], ll[4 + e]); }
        *(uint4*)a = make_uint4((uint)hh[0] | ((uint)hh[1] << 16), (uint)hh[2] | ((uint)hh[3] << 16),
                                (uint)hh[4] | ((uint)hh[5] << 16), (uint)hh[6] | ((uint)hh[7] << 16));
        *(uint4*)(a + 512) = make_uint4((uint)ll[0] | ((uint)ll[1] << 16), (uint)ll[2] | ((uint)ll[3] << 16),
                                        (uint)ll[4] | ((uint)ll[5] << 16), (uint)ll[6] | ((uint)ll[7] << 16));
      }
    }
    bar_lgkm();
    a2s[h] = fz;
    {
      const int pl = nfr * 16 + li;
#pragma unroll
      for (int ic = 0; ic < 8; ic++) {
        const uint4* wb = w2 + (((long)(blk * 4 + mfr) * 8 + ic) * 2) * 64 + lane;
        const bf16x8 Ah = asb(wb[0]), Al = asb(wb[64]);
        const char* ba = xb + pl * 1024 + ((ic * 64 + g * 16) ^ ((pl & 7) << 4));
        const bf16x8 bh = asb(*(const uint4*)ba);
        const bf16x8 bl = asb(*(const uint4*)(ba + 512));
        a2s[h] = MFMA_(Ah, bh, a2s[h]);
        a2s[h] = MFMA_(Ah, bl, a2s[h]);
        a2s[h] = MFMA_(Al, bh, a2s[h]);
      }
    }
  }
  bar_lgkm();   // all granule reads done; xt free for h2 floats

  // ---- h2 -> LDS floats (rows local 0..63 = this block's half) ----
  {
    float* h2L = (float*)xb;
    const int jl = mfr * 16 + g * 4;
#pragma unroll
    for (int h = 0; h < 2; h++) {
      const int pos = h * 64 + nfr * 16 + li;
      h2L[(jl + 0) * 128 + pos] = fmaxf(a2s[h][0] + b2[jl + 0], 0.f);
      h2L[(jl + 1) * 128 + pos] = fmaxf(a2s[h][1] + b2[jl + 1], 0.f);
      h2L[(jl + 2) * 128 + pos] = fmaxf(a2s[h][2] + b2[jl + 2], 0.f);
      h2L[(jl + 3) * 128 + pos] = fmaxf(a2s[h][3] + b2[jl + 3], 0.f);
    }
  }
  bar_lgkm();

  // ---- tail: blk0 -> pred3 + xy outputs; blk1 -> cls3 + sigmoid + NMS ----
  {
    const float* h2L = (const float*)xb;
    const int pp = t & 127;
    if (blk == 0) {
      if (t < 128) {
        float o0v = p3b[0], o1v = p3b[1];
        for (int j = 0; j < 64; j++) {
          const float hp = h2L[j * 128 + pp];
          o0v = fmaf(p3w[j], hp, o0v);
          o1v = fmaf(p3w[64 + j], hp, o1v);
        }
        const long ip = ((long)n * 128 + pp) * 2;
        out[ip + 0] = i_it[ip + 0] * 4.f + o0v;
        out[ip + 1] = i_it[ip + 1] * 4.f + o1v;
      }
    } else {
      float sig = 0.f;
      if (t < 128) {
        float cv = c3b[0];
        for (int j = 0; j < 64; j++) cv = fmaf(c3w[j], h2L[j * 128 + pp], cv);
        out[131072 + (long)n * 128 + pp] = cv;
        sig = 1.f / (1.f + expf(-cv));
        sg[pp] = sig;
      }
      bar_lgkm();
      if (t < 128) {
        float m = sg[pp];
#pragma unroll
        for (int s = 1; s <= 2; s++) {
          m = fmaxf(m, sg[(pp + s) & 127]);
          m = fmaxf(m, sg[(pp + 128 - s) & 127]);
        }
        out[196608 + (long)n * 128 + pp] = (sig >= m) ? sig : 0.f;
      }
    }
  }
}

extern "C" void kernel_launch(void* const* d_in, const int* in_sizes, int n_in,
                              void* d_out, int out_size, void* d_ws, size_t ws_size,
                              hipStream_t stream) {
  const float* cnn      = (const float*)d_in[0];
  const float* i_it     = (const float*)d_in[1];
  const float* c_it     = (const float*)d_in[2];
  const float* it_cls   = (const float*)d_in[3];
  const int*   ind      = (const int*)d_in[4];
  const float* head_w   = (const float*)d_in[5];
  const float* head_b   = (const float*)d_in[6];
  const float* res_w    = (const float*)d_in[7];
  const float* res_b    = (const float*)d_in[8];
  const float* fusion_w = (const float*)d_in[9];
  const float* fusion_b = (const float*)d_in[10];
  const float* pred1_w  = (const float*)d_in[11];
  const float* pred1_b  = (const float*)d_in[12];
  const float* pred2_w  = (const float*)d_in[13];
  const float* pred2_b  = (const float*)d_in[14];
  const float* pred3_w  = (const float*)d_in[15];
  const float* pred3_b  = (const float*)d_in[16];
  const float* cls1_w   = (const float*)d_in[17];
  const float* cls1_b   = (const float*)d_in[18];
  const float* cls2_w   = (const float*)d_in[19];
  const float* cls2_b   = (const float*)d_in[20];
  const float* cls3_w   = (const float*)d_in[21];
  const float* cls3_b   = (const float*)d_in[22];
  float* ws = (float*)d_ws;
  float* out = (float*)d_out;
  const ushort* wsu = (const ushort*)d_ws;

  k_repack<<<(int)((REPACK_N + 255) / 256), 256, 0, stream>>>(
      head_w, res_w, fusion_w, pred1_w, cls1_w, pred2_w, cls2_w, ws);

  long avail_f = (long)(ws_size / 4) - OFF_DYN;
  long Cl = avail_f / 131072;   // states: 131072 floats per poly
  int C = (Cl >= 512) ? 512 : ((Cl >= 256) ? 256 : (int)(Cl < 1 ? 1 : Cl));
  float* states = ws + OFF_DYN;

  for (int p0 = 0; p0 < 512; p0 += C) {
    int Cc = (512 - p0 < C) ? (512 - p0) : C;
    k_conv<<<Cc, 1024, 0, stream>>>(cnn, i_it, c_it, it_cls, ind,
                                    wsu + UOFF_CAW, wsu + UOFF_FAW, head_b, res_b,
                                    ws + OFF_GRAW, states, p0);
    k_h1t<<<2 * Cc, 1024, 0, stream>>>(states, wsu + UOFF_H1W, wsu + UOFF_W2F,
                                       ws + OFF_GRAW, fusion_b, ws + OFF_W1G,
                                       pred1_b, cls1_b, pred2_b, cls2_b,
                                       pred3_w, pred3_b, cls3_w, cls3_b,
                                       i_it, out, p0);
  }
}

// Round 10
// 925.678 us; speedup vs baseline: 1.4779x; 1.1038x over previous
//
#include <hip/hip_runtime.h>
#include <math.h>

typedef __attribute__((ext_vector_type(8))) short bf16x8;
typedef __attribute__((ext_vector_type(4))) float f32x4;

// ---------------- workspace layout ----------------
// ushort region (bf16 packed weights), offsets in ushorts:
#define UOFF_CAW 0L        // conv A  [l8][mp4][tap9][ic4][split2][mt2][lane64][e8] = 2359296 bf16
#define UOFF_FAW 2359296L  // fusion A [l8][fm2 8][ic4][split2][mt2][lane64][e8]   =  524288 bf16
#define UOFF_H1W 2883584L  // h1 A [blk2][mp8][slab8][ic4][split2][mt2][lane64][e8]= 1048576 bf16
#define UOFF_W2F 3932160L  // pred2/cls2 A [blk2][mfr4][ic8][split2][lane64][e8]   =   65536 bf16
#define NB_TOT   3997696L  // total bf16 elems (= 1998848 floats)
// float region, offsets in floats:
#define OFF_W1G  1998848L  // [c256][o512] = 131072
#define OFF_GRAW 2129920L  // [512][256] = 131072
#define OFF_DYN  2260992L  // dynamic: states (granule images, 131072 f/poly)
#define REPACK_N 4128768L  // NB_TOT + 131072

// ---------------- helpers ----------------
__device__ inline ushort f2bf_rne(float x) {
  uint u = __float_as_uint(x);
  return (ushort)((u + 0x7FFFu + ((u >> 16) & 1u)) >> 16);
}
__device__ inline void split_bf(float x, ushort& h, ushort& l) {
  uint u = __float_as_uint(x);
  uint hb = (u + 0x7FFFu + ((u >> 16) & 1u)) & 0xFFFF0000u;
  h = (ushort)(hb >> 16);
  l = f2bf_rne(x - __uint_as_float(hb));
}
__device__ inline ushort bfsel(float w, int split) {
  uint u = __float_as_uint(w);
  uint hb = (u + 0x7FFFu + ((u >> 16) & 1u)) & 0xFFFF0000u;
  if (split == 0) return (ushort)(hb >> 16);
  float lo = w - __uint_as_float(hb);
  uint ul = __float_as_uint(lo);
  return (ushort)((ul + 0x7FFFu + ((ul >> 16) & 1u)) >> 16);
}
__device__ inline bf16x8 asb(uint4 a) {
  union { uint4 u; bf16x8 v; } x; x.u = a; return x.v;
}
__device__ inline f32x4 MFMA_(bf16x8 a, bf16x8 b, f32x4 c) {
  return __builtin_amdgcn_mfma_f32_16x16x32_bf16(a, b, c, 0, 0, 0);
}
// lgkm-only barrier: does NOT drain vmcnt (weight loads / global stores stay in flight).
__device__ inline void bar_lgkm() {
  asm volatile("s_waitcnt lgkmcnt(0)" ::: "memory");
  __builtin_amdgcn_s_barrier();
}

// Granule image (64 KB): per position p (128 rows of 512 B), 16 hi-granules (16 B) + 16 lo.
// Granule (ic,g) holds bf16 of ch ic*32 + {4g..4g+3, 16+4g..16+4g+3} at byte (ic*64+g*16) ^ ((p&7)<<4);
// lo-plane at +256 B.
__device__ inline void read_frag_pair(const char* xb, int pc, int g, int ic,
                                      bf16x8& bh, bf16x8& bl) {
  const int s0 = (pc & 7) << 4;
  const char* a = xb + pc * 512 + (((ic * 64 + (g << 4))) ^ s0);
  bh = asb(*(const uint4*)a);
  bl = asb(*(const uint4*)(a + 256));
}

// ---------------- repack (unchanged) ----------------
__global__ void k_repack(const float* __restrict__ head_w, const float* __restrict__ res_w,
                         const float* __restrict__ fusion_w,
                         const float* __restrict__ pred1_w, const float* __restrict__ cls1_w,
                         const float* __restrict__ pred2_w, const float* __restrict__ cls2_w,
                         float* __restrict__ ws) {
  const long j = (long)blockIdx.x * 256 + threadIdx.x;
  if (j >= REPACK_N) return;
  if (j < NB_TOT) {
    ushort* wsu = (ushort*)ws;
    float w;
    if (j < UOFF_FAW) {                       // CAW
      int e = (int)(j & 7); long q = j >> 3;
      int lane = (int)(q & 63); q >>= 6;
      int mt = (int)(q & 1); q >>= 1;
      int split = (int)(q & 1); q >>= 1;
      int ic = (int)(q & 3); q >>= 2;
      int tap = (int)(q % 9); q /= 9;
      int mp = (int)(q & 3); int l = (int)(q >> 2);
      int gg = lane >> 4;
      int kl = (e < 4) ? (4 * gg + e) : (16 + 4 * gg + e - 4);
      int m = mp * 32 + mt * 16 + (lane & 15);
      int i = ic * 32 + kl;
      if (l == 0) w = (i < 67) ? head_w[((long)m * 67 + i) * 9 + tap] : 0.f;
      else        w = res_w[(((long)(l - 1) * 128 + m) * 128 + i) * 9 + tap];
      wsu[j] = bfsel(w, split);
    } else if (j < UOFF_H1W) {                // FAW
      long jj = j - UOFF_FAW;
      int e = (int)(jj & 7); long q = jj >> 3;
      int lane = (int)(q & 63); q >>= 6;
      int mt = (int)(q & 1); q >>= 1;
      int split = (int)(q & 1); q >>= 1;
      int ic = (int)(q & 3); q >>= 2;
      int fm2 = (int)(q & 7); int l = (int)(q >> 3);
      int gg = lane >> 4;
      int kl = (e < 4) ? (4 * gg + e) : (16 + 4 * gg + e - 4);
      int m = fm2 * 32 + mt * 16 + (lane & 15);
      int i = ic * 32 + kl;
      w = fusion_w[(long)m * 1024 + l * 128 + i];
      wsu[j] = bfsel(w, split);
    } else if (j < UOFF_W2F) {                // H1W
      long jj = j - UOFF_H1W;
      int e = (int)(jj & 7); long q = jj >> 3;
      int lane = (int)(q & 63); q >>= 6;
      int mt = (int)(q & 1); q >>= 1;
      int split = (int)(q & 1); q >>= 1;
      int ic = (int)(q & 3); q >>= 2;
      int slab = (int)(q & 7); q >>= 3;
      int mp = (int)(q & 7); int blk = (int)(q >> 3);
      int gg = lane >> 4;
      int kl = (e < 4) ? (4 * gg + e) : (16 + 4 * gg + e - 4);
      int m = blk * 256 + mp * 32 + mt * 16 + (lane & 15);
      int k = slab * 128 + ic * 32 + kl;
      w = (m < 256) ? pred1_w[(long)m * 1280 + 256 + k] : cls1_w[(long)(m - 256) * 1280 + 256 + k];
      wsu[j] = bfsel(w, split);
    } else {                                  // W2F (pred2/cls2 A-fragments)
      long jj = j - UOFF_W2F;
      int e = (int)(jj & 7); long q = jj >> 3;
      int lane = (int)(q & 63); q >>= 6;
      int split = (int)(q & 1); q >>= 1;
      int ic = (int)(q & 7); q >>= 3;
      int mfr = (int)(q & 3); int blk = (int)(q >> 2);
      int gg = lane >> 4;
      int kl = (e < 4) ? (4 * gg + e) : (16 + 4 * gg + e - 4);
      int m = mfr * 16 + (lane & 15);
      int k = ic * 32 + kl;
      w = blk ? cls2_w[(long)m * 256 + k] : pred2_w[(long)m * 256 + k];
      wsu[j] = bfsel(w, split);
    }
  } else {                                    // W1G (fp32)
    long q = j - NB_TOT; int o = (int)(q & 511); int c = (int)(q >> 9);
    ws[OFF_W1G + q] = (o < 256) ? pred1_w[(long)o * 1280 + c] : cls1_w[(long)(o - 256) * 1280 + c];
  }
}

// ================ K1: gather + 8-layer conv chain (unchanged from R9) ================
__global__ __launch_bounds__(1024) __attribute__((amdgpu_waves_per_eu(4)))
void k_conv(const float* __restrict__ cnn, const float* __restrict__ i_it,
            const float* __restrict__ c_it, const float* __restrict__ cls_in,
            const int* __restrict__ ind,
            const ushort* __restrict__ CAW, const ushort* __restrict__ FAW,
            const float* __restrict__ head_b, const float* __restrict__ res_b,
            float* __restrict__ graw, float* __restrict__ states, int p0) {
  __shared__ uint4 xt4[4096];   // 64 KB granule image
  __shared__ float scr[512];
  char* xb = (char*)xt4;
  const int ln = blockIdx.x, n = p0 + ln, t = threadIdx.x;
  const int lane = t & 63, li = lane & 15, g = lane >> 4;
  const int wv = __builtin_amdgcn_readfirstlane(t >> 6);
  const int mp = wv & 3, np = wv >> 2;     // conv: M=32 ch x N=32 pos per wave
  const int fm2 = wv & 7, fq = wv >> 3;    // fusion: M=32 of 256 x N=64 pos per wave

  // ---- bilinear gather -> LDS fragment granules ----
  {
    const int p = t & 127, qg = t >> 7;
    const long nb = (long)n * 128 + p;
    const int sw = p & 7;
    if (qg < 4) {
      const float gx = i_it[nb * 2 + 0] - 0.5f;
      const float gy = i_it[nb * 2 + 1] - 0.5f;
      const float fx = floorf(gx), fy = floorf(gy);
      const float wx = gx - fx, wy = gy - fy;
      const int x0 = (int)fx, y0 = (int)fy, x1 = x0 + 1, y1 = y0 + 1;
      const bool vx0 = (x0 >= 0) & (x0 < 128), vx1 = (x1 >= 0) & (x1 < 128);
      const bool vy0 = (y0 >= 0) & (y0 < 128), vy1 = (y1 >= 0) & (y1 < 128);
      const int x0c = min(max(x0, 0), 127), x1c = min(max(x1, 0), 127);
      const int y0c = min(max(y0, 0), 127), y1c = min(max(y1, 0), 127);
      const float w00 = (vx0 && vy0) ? (1.f - wx) * (1.f - wy) : 0.f;
      const float w01 = (vx1 && vy0) ? wx * (1.f - wy) : 0.f;
      const float w10 = (vx0 && vy1) ? (1.f - wx) * wy : 0.f;
      const float w11 = (vx1 && vy1) ? wx * wy : 0.f;
      const long base = (long)ind[n] * (64L * 16384);
      const int a00 = y0c * 128 + x0c, a01 = y0c * 128 + x1c;
      const int a10 = y1c * 128 + x0c, a11 = y1c * 128 + x1c;
#pragma unroll
      for (int qq = 0; qq < 4; qq++) {
        ushort hh[4], ll[4];
#pragma unroll
        for (int cc = 0; cc < 4; cc++) {
          const int c = qg * 16 + qq * 4 + cc;
          const float* f = cnn + base + (long)c * 16384;
          float x = f[a00] * w00 + f[a01] * w01 + f[a10] * w10 + f[a11] * w11;
          split_bf(x, hh[cc], ll[cc]);
        }
        const int G = ((qg >> 1) * 4 + qq) ^ sw;
        char* a = xb + p * 512 + G * 16 + (qg & 1) * 8;
        *(uint2*)a = make_uint2((uint)hh[0] | ((uint)hh[1] << 16), (uint)hh[2] | ((uint)hh[3] << 16));
        *(uint2*)(a + 256) = make_uint2((uint)ll[0] | ((uint)ll[1] << 16), (uint)ll[2] | ((uint)ll[3] << 16));
      }
    } else {
#pragma unroll
      for (int qq = 0; qq < 4; qq++) {
        ushort hh[4], ll[4];
        if (qg == 4 && qq == 0) {
          float v0 = c_it[nb * 2 + 0] * 4.f, v1 = c_it[nb * 2 + 1] * 4.f, v2 = cls_in[nb];
          split_bf(v0, hh[0], ll[0]); split_bf(v1, hh[1], ll[1]); split_bf(v2, hh[2], ll[2]);
          hh[3] = 0; ll[3] = 0;
        } else {
          hh[0] = hh[1] = hh[2] = hh[3] = 0; ll[0] = ll[1] = ll[2] = ll[3] = 0;
        }
        const int G = ((qg >> 1) * 4 + qq) ^ sw;
        char* a = xb + p * 512 + G * 16 + (qg & 1) * 8;
        *(uint2*)a = make_uint2((uint)hh[0] | ((uint)hh[1] << 16), (uint)hh[2] | ((uint)hh[3] << 16));
        *(uint2*)(a + 256) = make_uint2((uint)ll[0] | ((uint)ll[1] << 16), (uint)ll[2] | ((uint)ll[3] << 16));
      }
    }
  }
  __syncthreads();

  const f32x4 fz = {0.f, 0.f, 0.f, 0.f};
  f32x4 facc[2][4];
#pragma unroll
  for (int a = 0; a < 2; a++)
#pragma unroll
    for (int b = 0; b < 4; b++) facc[a][b] = fz;

  const uint4* caw = (const uint4*)CAW;
  const uint4* faw = (const uint4*)FAW;
  uint4* stq = (uint4*)(states + (long)ln * 131072);

  for (int l = 0; l < 8; l++) {
    const int dil = (l >= 6) ? 4 : ((l >= 4) ? 2 : 1);
    const int nic = (l == 0) ? 3 : 4;
    // ======== READ REGION: copy(l-1) + fusion(l-1) + conv(l), all read xt ========
    if (l > 0) {
      uint4* dst = stq + (long)(l - 1) * 4096;
#pragma unroll
      for (int k = 0; k < 4; k++) dst[k * 1024 + t] = xt4[k * 1024 + t];
      const uint4* fawl = faw + ((long)((l - 1) * 8 + fm2)) * 1024 + lane;
#pragma unroll
      for (int ic = 0; ic < 4; ic++) {
        const uint4* w0 = fawl + ic * 256;
        const bf16x8 Ah0 = asb(w0[0]),   Ah1 = asb(w0[64]);
        const bf16x8 Al0 = asb(w0[128]), Al1 = asb(w0[192]);
#pragma unroll
        for (int nt = 0; nt < 4; nt++) {
          const int pc = fq * 64 + nt * 16 + li;
          bf16x8 bh, bl;
          read_frag_pair(xb, pc, g, ic, bh, bl);
          facc[0][nt] = MFMA_(Ah0, bh, facc[0][nt]);
          facc[1][nt] = MFMA_(Ah1, bh, facc[1][nt]);
          facc[0][nt] = MFMA_(Ah0, bl, facc[0][nt]);
          facc[1][nt] = MFMA_(Ah1, bl, facc[1][nt]);
          facc[0][nt] = MFMA_(Al0, bh, facc[0][nt]);
          facc[1][nt] = MFMA_(Al1, bh, facc[1][nt]);
        }
      }
    }
    // conv(l)
    f32x4 cacc[2][2];
    cacc[0][0] = fz; cacc[0][1] = fz; cacc[1][0] = fz; cacc[1][1] = fz;
    const uint4* cawl = caw + ((long)(l * 4 + mp)) * 9216;
    for (int tap = 0; tap < 9; tap++) {
      const int shift = (tap - 4) * dil;
      const int pc0 = (np * 32 + li + shift + 128) & 127;
      const int pc1 = (np * 32 + 16 + li + shift + 128) & 127;
      const uint4* cawt = cawl + tap * 1024 + lane;
      for (int ic = 0; ic < nic; ic++) {
        bf16x8 bh0, bl0, bh1, bl1;
        read_frag_pair(xb, pc0, g, ic, bh0, bl0);
        read_frag_pair(xb, pc1, g, ic, bh1, bl1);
        const uint4* w0 = cawt + ic * 256;
        const bf16x8 Ah0 = asb(w0[0]),   Ah1 = asb(w0[64]);
        const bf16x8 Al0 = asb(w0[128]), Al1 = asb(w0[192]);
        cacc[0][0] = MFMA_(Ah0, bh0, cacc[0][0]);
        cacc[0][1] = MFMA_(Ah0, bh1, cacc[0][1]);
        cacc[1][0] = MFMA_(Ah1, bh0, cacc[1][0]);
        cacc[1][1] = MFMA_(Ah1, bh1, cacc[1][1]);
        cacc[0][0] = MFMA_(Ah0, bl0, cacc[0][0]);
        cacc[0][1] = MFMA_(Ah0, bl1, cacc[0][1]);
        cacc[1][0] = MFMA_(Ah1, bl0, cacc[1][0]);
        cacc[1][1] = MFMA_(Ah1, bl1, cacc[1][1]);
        cacc[0][0] = MFMA_(Al0, bh0, cacc[0][0]);
        cacc[0][1] = MFMA_(Al0, bh1, cacc[0][1]);
        cacc[1][0] = MFMA_(Al1, bh0, cacc[1][0]);
        cacc[1][1] = MFMA_(Al1, bh1, cacc[1][1]);
      }
    }
    bar_lgkm();
    // ======== EPILOGUE: bias + relu + residual -> xt granules ========
    {
      const float* bsrc = (l == 0) ? head_b : (res_b + (l - 1) * 128);
      const float4 b0 = *(const float4*)&bsrc[mp * 32 + g * 4];
      const float4 b1 = *(const float4*)&bsrc[mp * 32 + 16 + g * 4];
#pragma unroll
      for (int nt = 0; nt < 2; nt++) {
        const int p = np * 32 + nt * 16 + li;
        const int X = (mp * 64 + g * 16) ^ ((p & 7) << 4);
        char* a = xb + p * 512 + X;
        float v[8];
        v[0] = fmaxf(cacc[0][nt][0] + b0.x, 0.f);
        v[1] = fmaxf(cacc[0][nt][1] + b0.y, 0.f);
        v[2] = fmaxf(cacc[0][nt][2] + b0.z, 0.f);
        v[3] = fmaxf(cacc[0][nt][3] + b0.w, 0.f);
        v[4] = fmaxf(cacc[1][nt][0] + b1.x, 0.f);
        v[5] = fmaxf(cacc[1][nt][1] + b1.y, 0.f);
        v[6] = fmaxf(cacc[1][nt][2] + b1.z, 0.f);
        v[7] = fmaxf(cacc[1][nt][3] + b1.w, 0.f);
        if (l > 0) {
          const uint4 oh = *(const uint4*)a;
          const uint4 ol = *(const uint4*)(a + 256);
          const uint hw[4] = {oh.x, oh.y, oh.z, oh.w};
          const uint lw[4] = {ol.x, ol.y, ol.z, ol.w};
#pragma unroll
          for (int k = 0; k < 8; k++) {
            const uint hh = (k & 1) ? (hw[k >> 1] & 0xFFFF0000u) : ((hw[k >> 1] & 0xFFFFu) << 16);
            const uint ll = (k & 1) ? (lw[k >> 1] & 0xFFFF0000u) : ((lw[k >> 1] & 0xFFFFu) << 16);
            v[k] += __uint_as_float(hh) + __uint_as_float(ll);
          }
        }
        ushort hh[8], ll[8];
#pragma unroll
        for (int k = 0; k < 8; k++) split_bf(v[k], hh[k], ll[k]);
        *(uint4*)a = make_uint4((uint)hh[0] | ((uint)hh[1] << 16), (uint)hh[2] | ((uint)hh[3] << 16),
                                (uint)hh[4] | ((uint)hh[5] << 16), (uint)hh[6] | ((uint)hh[7] << 16));
        *(uint4*)(a + 256) = make_uint4((uint)ll[0] | ((uint)ll[1] << 16), (uint)ll[2] | ((uint)ll[3] << 16),
                                        (uint)ll[4] | ((uint)ll[5] << 16), (uint)ll[6] | ((uint)ll[7] << 16));
      }
    }
    __syncthreads();
  }

  // ======== tail: copy(7) + fusion(7) ========
  {
    uint4* dst = stq + 7L * 4096;
#pragma unroll
    for (int k = 0; k < 4; k++) dst[k * 1024 + t] = xt4[k * 1024 + t];
    const uint4* fawl = faw + ((long)(7 * 8 + fm2)) * 1024 + lane;
#pragma unroll
    for (int ic = 0; ic < 4; ic++) {
      const uint4* w0 = fawl + ic * 256;
      const bf16x8 Ah0 = asb(w0[0]),   Ah1 = asb(w0[64]);
      const bf16x8 Al0 = asb(w0[128]), Al1 = asb(w0[192]);
#pragma unroll
      for (int nt = 0; nt < 4; nt++) {
        const int pc = fq * 64 + nt * 16 + li;
        bf16x8 bh, bl;
        read_frag_pair(xb, pc, g, ic, bh, bl);
        facc[0][nt] = MFMA_(Ah0, bh, facc[0][nt]);
        facc[1][nt] = MFMA_(Ah1, bh, facc[1][nt]);
        facc[0][nt] = MFMA_(Ah0, bl, facc[0][nt]);
        facc[1][nt] = MFMA_(Ah1, bl, facc[1][nt]);
        facc[0][nt] = MFMA_(Al0, bh, facc[0][nt]);
        facc[1][nt] = MFMA_(Al1, bh, facc[1][nt]);
      }
    }
  }

  // ---- fusion row-max over 128 positions -> graw ----
#pragma unroll
  for (int mt = 0; mt < 2; mt++) {
#pragma unroll
    for (int r = 0; r < 4; r++) {
      float m = fmaxf(fmaxf(facc[mt][0][r], facc[mt][1][r]),
                      fmaxf(facc[mt][2][r], facc[mt][3][r]));
#pragma unroll
      for (int s = 1; s < 16; s <<= 1) m = fmaxf(m, __shfl_xor(m, s, 64));
      if (li == 0) scr[(fm2 * 32 + mt * 16 + g * 4 + r) * 2 + fq] = m;
    }
  }
  bar_lgkm();
  if (t < 256) graw[(long)n * 256 + t] = fmaxf(scr[2 * t], scr[2 * t + 1]);
}

// =============== K2: hg + h1 + pred2/cls2 + pred3/cls3 + NMS — ONE block per poly ===============
// States read once; 128 KB double-buffered slab pipeline (1 barrier per slab).
__global__ __launch_bounds__(1024) __attribute__((amdgpu_waves_per_eu(4)))
void k_h1t(const float* __restrict__ states, const ushort* __restrict__ H1W,
           const ushort* __restrict__ W2F,
           const float* __restrict__ graw, const float* __restrict__ fus_b,
           const float* __restrict__ W1G, const float* __restrict__ p1b, const float* __restrict__ c1b,
           const float* __restrict__ p2b, const float* __restrict__ c2b,
           const float* __restrict__ p3w, const float* __restrict__ p3b,
           const float* __restrict__ c3w, const float* __restrict__ c3b,
           const float* __restrict__ i_it, float* __restrict__ out, int p0) {
  __shared__ uint4 xt4[8192];   // 128 KB: slab double-buffer; later quarter image + h2 floats in buf0
  __shared__ float sg[256];
  __shared__ float hg_s[512];
  char* xb = (char*)xt4;
  const int ln = blockIdx.x, n = p0 + ln, t = threadIdx.x;
  const int lane = t & 63, li = lane & 15, g = lane >> 4;
  const int wv = __builtin_amdgcn_readfirstlane(t >> 6);
  const uint4* sp = (const uint4*)(states + (long)ln * 131072);
  const uint4* aw = (const uint4*)H1W;
  const uint4* w2 = (const uint4*)W2F;
  const f32x4 fz = {0.f, 0.f, 0.f, 0.f};

  // issue slab-0 loads immediately
  uint4 stg[4];
#pragma unroll
  for (int k = 0; k < 4; k++) stg[k] = sp[k * 1024 + t];

  // ---- phase A: hg[512] ----
  if (t < 256) sg[t] = graw[(long)n * 256 + t] + fus_b[t];
  bar_lgkm();
  // write slab 0 into buf0 (waits on vmcnt implicitly)
#pragma unroll
  for (int k = 0; k < 4; k++) xt4[k * 1024 + t] = stg[k];
  if (t < 512) {
    float s = (t < 256) ? p1b[t] : c1b[t - 256];
    const float* w = W1G + t;
#pragma unroll 8
    for (int c = 0; c < 256; c++) s = fmaf(w[(long)c * 512], sg[c], s);
    hg_s[t] = s;
  }
  bar_lgkm();   // buf0 + hg_s visible

  // ---- phase B: h1 = W1H @ states; wave wv owns rows wv*32..wv*32+31, all 128 pos ----
  f32x4 acc[2][8];
#pragma unroll
  for (int a = 0; a < 2; a++)
#pragma unroll
    for (int c = 0; c < 8; c++) acc[a][c] = fz;

  for (int s = 0; s < 8; s++) {
    if (s < 7) {
#pragma unroll
      for (int k = 0; k < 4; k++) stg[k] = sp[(long)(s + 1) * 4096 + k * 1024 + t];
    }
    const char* xc = xb + (s & 1) * 65536;
    const uint4* awl = aw + ((long)(wv * 8 + s)) * 1024 + lane;  // (blk*8+mw)*8+s with wv=blk*8+mw
#pragma unroll
    for (int ic = 0; ic < 4; ic++) {
      const uint4* w0 = awl + ic * 256;
      const bf16x8 Ah0 = asb(w0[0]),   Ah1 = asb(w0[64]);
      const bf16x8 Al0 = asb(w0[128]), Al1 = asb(w0[192]);
#pragma unroll
      for (int nt = 0; nt < 8; nt++) {
        const int pc = nt * 16 + li;
        bf16x8 bh, bl;
        read_frag_pair(xc, pc, g, ic, bh, bl);
        acc[0][nt] = MFMA_(Ah0, bh, acc[0][nt]);
        acc[1][nt] = MFMA_(Ah1, bh, acc[1][nt]);
        acc[0][nt] = MFMA_(Ah0, bl, acc[0][nt]);
        acc[1][nt] = MFMA_(Ah1, bl, acc[1][nt]);
        acc[0][nt] = MFMA_(Al0, bh, acc[0][nt]);
        acc[1][nt] = MFMA_(Al1, bh, acc[1][nt]);
      }
    }
    if (s < 7) {
      uint4* dbuf = xt4 + ((s + 1) & 1) * 4096;
#pragma unroll
      for (int k = 0; k < 4; k++) dbuf[k * 1024 + t] = stg[k];
    }
    bar_lgkm();   // orders: next-slab writes before next reads; this slab's reads before overwrite
  }

  // h1 bias + relu in regs: row = wv*32 + mt*16 + g*4 + e
  const float4 hq0 = *(const float4*)&hg_s[wv * 32 + g * 4];
  const float4 hq1 = *(const float4*)&hg_s[wv * 32 + 16 + g * 4];
#pragma unroll
  for (int nt = 0; nt < 8; nt++) {
    acc[0][nt][0] = fmaxf(acc[0][nt][0] + hq0.x, 0.f);
    acc[0][nt][1] = fmaxf(acc[0][nt][1] + hq0.y, 0.f);
    acc[0][nt][2] = fmaxf(acc[0][nt][2] + hq0.z, 0.f);
    acc[0][nt][3] = fmaxf(acc[0][nt][3] + hq0.w, 0.f);
    acc[1][nt][0] = fmaxf(acc[1][nt][0] + hq1.x, 0.f);
    acc[1][nt][1] = fmaxf(acc[1][nt][1] + hq1.y, 0.f);
    acc[1][nt][2] = fmaxf(acc[1][nt][2] + hq1.z, 0.f);
    acc[1][nt][3] = fmaxf(acc[1][nt][3] + hq1.w, 0.f);
  }

  // ---- phase C: h2 = W2 @ h1, 4 pos-quarters; quarter image (64 KB, buf0):
  // pos pl (32 rows of 2 KB): hi granule (kc,gp) at pl*2048 + ((kc*64+gp*16)^((pl&7)<<4)), lo +1024.
  // Writer wave wv -> kc=wv, gp=g, 8B-half mt. Reader: wave -> h2 frag (mf=wv>>1, nf=wv&1).
  const int mf = wv >> 1, nf = wv & 1;
  const int blkc = mf >> 2, mfr = mf & 3;
  f32x4 a2q[4];
#pragma unroll
  for (int q = 0; q < 4; q++) {
    // stage h1 rows for pos-quarter q (nt = 2q, 2q+1)
#pragma unroll
    for (int mt = 0; mt < 2; mt++) {
#pragma unroll
      for (int ntl = 0; ntl < 2; ntl++) {
        const int nt = 2 * q + ntl;
        const int pl = ntl * 16 + li;
        char* a = xb + pl * 2048 + ((wv * 64 + g * 16) ^ ((pl & 7) << 4)) + mt * 8;
        ushort hh[4], llw[4];
        split_bf(acc[mt][nt][0], hh[0], llw[0]);
        split_bf(acc[mt][nt][1], hh[1], llw[1]);
        split_bf(acc[mt][nt][2], hh[2], llw[2]);
        split_bf(acc[mt][nt][3], hh[3], llw[3]);
        *(uint2*)a = make_uint2((uint)hh[0] | ((uint)hh[1] << 16), (uint)hh[2] | ((uint)hh[3] << 16));
        *(uint2*)(a + 1024) = make_uint2((uint)llw[0] | ((uint)llw[1] << 16), (uint)llw[2] | ((uint)llw[3] << 16));
      }
    }
    bar_lgkm();
    a2q[q] = fz;
    {
      const int pl = nf * 16 + li;
#pragma unroll
      for (int ic = 0; ic < 8; ic++) {
        const int kc = blkc * 8 + ic;
        const uint4* wb = w2 + (((long)(blkc * 4 + mfr) * 8 + ic) * 2) * 64 + lane;
        const bf16x8 Ah = asb(wb[0]), Al = asb(wb[64]);
        const char* ba = xb + pl * 2048 + ((kc * 64 + g * 16) ^ ((pl & 7) << 4));
        const bf16x8 bh = asb(*(const uint4*)ba);
        const bf16x8 bl = asb(*(const uint4*)(ba + 1024));
        a2q[q] = MFMA_(Ah, bh, a2q[q]);
        a2q[q] = MFMA_(Ah, bl, a2q[q]);
        a2q[q] = MFMA_(Al, bh, a2q[q]);
      }
    }
    bar_lgkm();   // reads done before next quarter's writers overwrite
  }

  // ---- h2 -> LDS floats [128 rows][128 pos] in buf0 ----
  {
    float* h2L = (float*)xb;
    const int row0 = mf * 16 + g * 4;
    const float4 b2v = (mf < 4) ? *(const float4*)&p2b[row0]
                                : *(const float4*)&c2b[row0 - 64];
#pragma unroll
    for (int q = 0; q < 4; q++) {
      const int pos = q * 32 + nf * 16 + li;
      h2L[(row0 + 0) * 128 + pos] = fmaxf(a2q[q][0] + b2v.x, 0.f);
      h2L[(row0 + 1) * 128 + pos] = fmaxf(a2q[q][1] + b2v.y, 0.f);
      h2L[(row0 + 2) * 128 + pos] = fmaxf(a2q[q][2] + b2v.z, 0.f);
      h2L[(row0 + 3) * 128 + pos] = fmaxf(a2q[q][3] + b2v.w, 0.f);
    }
  }
  bar_lgkm();

  // ---- tail: pred3 (rows 0..63) + cls3 (rows 64..127) + sigmoid + NMS ----
  {
    const float* h2L = (const float*)xb;
    const int pp = t & 127;
    float sig = 0.f;
    if (t < 128) {
      float o0v = p3b[0], o1v = p3b[1], cv = c3b[0];
      for (int j = 0; j < 64; j++) {
        const float hp = h2L[j * 128 + pp];
        const float hc = h2L[(64 + j) * 128 + pp];
        o0v = fmaf(p3w[j], hp, o0v);
        o1v = fmaf(p3w[64 + j], hp, o1v);
        cv = fmaf(c3w[j], hc, cv);
      }
      const long ip = ((long)n * 128 + pp) * 2;
      out[ip + 0] = i_it[ip + 0] * 4.f + o0v;
      out[ip + 1] = i_it[ip + 1] * 4.f + o1v;
      out[131072 + (long)n * 128 + pp] = cv;
      sig = 1.f / (1.f + expf(-cv));
      sg[pp] = sig;
    }
    bar_lgkm();
    if (t < 128) {
      float m = sg[pp];
#pragma unroll
      for (int s = 1; s <= 2; s++) {
        m = fmaxf(m, sg[(pp + s) & 127]);
        m = fmaxf(m, sg[(pp + 128 - s) & 127]);
      }
      out[196608 + (long)n * 128 + pp] = (sig >= m) ? sig : 0.f;
    }
  }
}

extern "C" void kernel_launch(void* const* d_in, const int* in_sizes, int n_in,
                              void* d_out, int out_size, void* d_ws, size_t ws_size,
                              hipStream_t stream) {
  const float* cnn      = (const float*)d_in[0];
  const float* i_it     = (const float*)d_in[1];
  const float* c_it     = (const float*)d_in[2];
  const float* it_cls   = (const float*)d_in[3];
  const int*   ind      = (const int*)d_in[4];
  const float* head_w   = (const float*)d_in[5];
  const float* head_b   = (const float*)d_in[6];
  const float* res_w    = (const float*)d_in[7];
  const float* res_b    = (const float*)d_in[8];
  const float* fusion_w = (const float*)d_in[9];
  const float* fusion_b = (const float*)d_in[10];
  const float* pred1_w  = (const float*)d_in[11];
  const float* pred1_b  = (const float*)d_in[12];
  const float* pred2_w  = (const float*)d_in[13];
  const float* pred2_b  = (const float*)d_in[14];
  const float* pred3_w  = (const float*)d_in[15];
  const float* pred3_b  = (const float*)d_in[16];
  const float* cls1_w   = (const float*)d_in[17];
  const float* cls1_b   = (const float*)d_in[18];
  const float* cls2_w   = (const float*)d_in[19];
  const float* cls2_b   = (const float*)d_in[20];
  const float* cls3_w   = (const float*)d_in[21];
  const float* cls3_b   = (const float*)d_in[22];
  float* ws = (float*)d_ws;
  float* out = (float*)d_out;
  const ushort* wsu = (const ushort*)d_ws;

  k_repack<<<(int)((REPACK_N + 255) / 256), 256, 0, stream>>>(
      head_w, res_w, fusion_w, pred1_w, cls1_w, pred2_w, cls2_w, ws);

  long avail_f = (long)(ws_size / 4) - OFF_DYN;
  long Cl = avail_f / 131072;   // states: 131072 floats per poly
  int C = (Cl >= 512) ? 512 : ((Cl >= 256) ? 256 : (int)(Cl < 1 ? 1 : Cl));
  float* states = ws + OFF_DYN;

  for (int p0 = 0; p0 < 512; p0 += C) {
    int Cc = (512 - p0 < C) ? (512 - p0) : C;
    k_conv<<<Cc, 1024, 0, stream>>>(cnn, i_it, c_it, it_cls, ind,
                                    wsu + UOFF_CAW, wsu + UOFF_FAW, head_b, res_b,
                                    ws + OFF_GRAW, states, p0);
    k_h1t<<<Cc, 1024, 0, stream>>>(states, wsu + UOFF_H1W, wsu + UOFF_W2F,
                                   ws + OFF_GRAW, fusion_b, ws + OFF_W1G,
                                   pred1_b, cls1_b, pred2_b, cls2_b,
                                   pred3_w, pred3_b, cls3_w, cls3_b,
                                   i_it, out, p0);
  }
}